// Round 4
// baseline (416.592 us; speedup 1.0000x reference)
//
#include <hip/hip_runtime.h>

typedef __bf16 bf16;
typedef bf16 bf16x8 __attribute__((ext_vector_type(8)));
typedef bf16 bf16x4 __attribute__((ext_vector_type(4)));
typedef float f32x4 __attribute__((ext_vector_type(4)));

// ---------------------------------------------------------------------------
// async global->LDS 16B copy (wave-uniform LDS base + lane*16 placement)
// ---------------------------------------------------------------------------
static __device__ __forceinline__ void async16(const void* g, void* l) {
  __builtin_amdgcn_global_load_lds((__attribute__((address_space(1))) void*)g,
                                   (__attribute__((address_space(3))) void*)l,
                                   16, 0, 0);
}

// DPP row_ror:N within 16-lane rows (VALU-only cross-lane; no LDS pipe).
template <int N>
static __device__ __forceinline__ float ror16(float x) {
  const int y =
      __builtin_amdgcn_update_dpp(0, __float_as_int(x), 0x120 | N, 0xf, 0xf, true);
  return __int_as_float(y);
}
static __device__ __forceinline__ float rowmax16(float x) {
  x = fmaxf(x, ror16<8>(x));
  x = fmaxf(x, ror16<4>(x));
  x = fmaxf(x, ror16<2>(x));
  x = fmaxf(x, ror16<1>(x));
  return x;
}

// ---------------------------------------------------------------------------
// LN1 (split bf16 hi/lo) fused with cvt4 (attention weights f32->bf16).
// blocks [0,4096): LN rows; blocks [4096,8192): weight conversion chunks.
// ---------------------------------------------------------------------------
__global__ __launch_bounds__(256) void ln1_cvt4(
    const float* __restrict__ x, const float* __restrict__ g,
    const float* __restrict__ b, bf16* __restrict__ hi, bf16* __restrict__ lo,
    const float* __restrict__ Wq, const float* __restrict__ Wk,
    const float* __restrict__ Wv, const float* __restrict__ Wo,
    bf16* __restrict__ wdst) {
  const int tid = threadIdx.x;
  if (blockIdx.x >= 4096) {  // cvt4 path
    const size_t i = ((size_t)(blockIdx.x - 4096) * 256 + tid) * 4;
    const size_t M1 = 1u << 20;
    const float* src = (i < M1) ? Wq : (i < 2 * M1) ? Wk : (i < 3 * M1) ? Wv : Wo;
    const size_t off = i & (M1 - 1);
    const float4 v = *(const float4*)(src + off);
    bf16x4 o = {(bf16)v.x, (bf16)v.y, (bf16)v.z, (bf16)v.w};
    *(bf16x4*)(wdst + i) = o;
    return;
  }
  const int row = blockIdx.x;
  const float* xr = x + (size_t)row * 1024;
  float v[4];
  float s1 = 0.f, s2 = 0.f;
#pragma unroll
  for (int j = 0; j < 4; ++j) {
    v[j] = xr[j * 256 + tid];
    s1 += v[j];
    s2 += v[j] * v[j];
  }
#pragma unroll
  for (int off = 1; off < 64; off <<= 1) {
    s1 += __shfl_xor(s1, off);
    s2 += __shfl_xor(s2, off);
  }
  __shared__ float ws1[4], ws2[4];
  const int wid = tid >> 6;
  if ((tid & 63) == 0) {
    ws1[wid] = s1;
    ws2[wid] = s2;
  }
  __syncthreads();
  s1 = ws1[0] + ws1[1] + ws1[2] + ws1[3];
  s2 = ws2[0] + ws2[1] + ws2[2] + ws2[3];
  const float mu = s1 * (1.f / 1024.f);
  const float var = s2 * (1.f / 1024.f) - mu * mu;
  const float rstd = 1.0f / sqrtf(var + 1e-5f);
#pragma unroll
  for (int j = 0; j < 4; ++j) {
    const int cc = j * 256 + tid;
    const float y = (v[j] - mu) * rstd * g[cc] + b[cc];
    const bf16 yh = (bf16)y;
    hi[(size_t)row * 1024 + cc] = yh;
    lo[(size_t)row * 1024 + cc] = (bf16)(y - (float)yh);
  }
}

// ---------------------------------------------------------------------------
// LayerNorm over D=1024 (f32 input), one block per row (non-split).
// ---------------------------------------------------------------------------
__global__ __launch_bounds__(256) void ln_kernel(
    const float* __restrict__ x, const float* __restrict__ g,
    const float* __restrict__ b, bf16* __restrict__ hi) {
  const int row = blockIdx.x;
  const int tid = threadIdx.x;
  const float* xr = x + (size_t)row * 1024;
  float v[4];
  float s1 = 0.f, s2 = 0.f;
#pragma unroll
  for (int j = 0; j < 4; ++j) {
    v[j] = xr[j * 256 + tid];
    s1 += v[j];
    s2 += v[j] * v[j];
  }
#pragma unroll
  for (int off = 1; off < 64; off <<= 1) {
    s1 += __shfl_xor(s1, off);
    s2 += __shfl_xor(s2, off);
  }
  __shared__ float ws1[4], ws2[4];
  const int wid = tid >> 6;
  if ((tid & 63) == 0) {
    ws1[wid] = s1;
    ws2[wid] = s2;
  }
  __syncthreads();
  s1 = ws1[0] + ws1[1] + ws1[2] + ws1[3];
  s2 = ws2[0] + ws2[1] + ws2[2] + ws2[3];
  const float mu = s1 * (1.f / 1024.f);
  const float var = s2 * (1.f / 1024.f) - mu * mu;
  const float rstd = 1.0f / sqrtf(var + 1e-5f);
#pragma unroll
  for (int j = 0; j < 4; ++j) {
    const int cc = j * 256 + tid;
    const float y = (v[j] - mu) * rstd * g[cc] + b[cc];
    hi[(size_t)row * 1024 + cc] = (bf16)y;
  }
}

// ---------------------------------------------------------------------------
// GEMM body: C[M,N] = A[M,K] * B[N,K]^T   (m97 structure, BK=64 as two BK=32
// sub-buffers per barrier pair). Used by gemm_qkv (EPI=5 V^T path).
// ---------------------------------------------------------------------------
template <int EPI>
static __device__ __forceinline__ void gemm_body(
    const bf16* __restrict__ A, const bf16* __restrict__ B,
    void* __restrict__ Cv, const float* __restrict__ R, bf16* smem, int col0,
    int row0, int M, int N, int K) {
  bf16* sA0 = smem;          // 128 x 32
  bf16* sA1 = smem + 4096;   // 128 x 32 (k+32)
  bf16* sB0 = smem + 8192;   // 128 x 32
  bf16* sB1 = smem + 12288;  // 128 x 32 (k+32)
  const int tid = threadIdx.x;
  const int lane = tid & 63;
  const int wid = tid >> 6;
  const int wm = wid >> 1, wn = wid & 1;

  f32x4 acc[4][4];
  const f32x4 fzero = {0.f, 0.f, 0.f, 0.f};
#pragma unroll
  for (int i = 0; i < 4; ++i)
#pragma unroll
    for (int j = 0; j < 4; ++j) acc[i][j] = fzero;

  const int nk = K >> 6;
  const int r0 = tid >> 2, c0 = (tid & 3) << 3;
  const int r1 = (256 + tid) >> 2, c1 = ((256 + tid) & 3) << 3;
  const int wofs0 = (wid << 6) * 8;  // wave-uniform LDS offsets
  const int wofs1 = (256 + (wid << 6)) * 8;

  for (int kt = 0; kt < nk; ++kt) {
    const int k0 = kt << 6;
    async16(A + (size_t)(row0 + r0) * K + k0 + c0, sA0 + wofs0);
    async16(A + (size_t)(row0 + r1) * K + k0 + c1, sA0 + wofs1);
    async16(A + (size_t)(row0 + r0) * K + k0 + 32 + c0, sA1 + wofs0);
    async16(A + (size_t)(row0 + r1) * K + k0 + 32 + c1, sA1 + wofs1);
    async16(B + (size_t)(col0 + r0) * K + k0 + c0, sB0 + wofs0);
    async16(B + (size_t)(col0 + r1) * K + k0 + c1, sB0 + wofs1);
    async16(B + (size_t)(col0 + r0) * K + k0 + 32 + c0, sB1 + wofs0);
    async16(B + (size_t)(col0 + r1) * K + k0 + 32 + c1, sB1 + wofs1);
    __syncthreads();
    const int fr = lane & 15, fq = (lane >> 4) << 3;
#pragma unroll
    for (int t = 0; t < 2; ++t) {
      const bf16* sA = t ? sA1 : sA0;
      const bf16* sB = t ? sB1 : sB0;
      bf16x8 af[4], bfr[4];
#pragma unroll
      for (int i = 0; i < 4; ++i)
        af[i] = *(const bf16x8*)&sA[(wm * 64 + i * 16 + fr) * 32 + fq];
#pragma unroll
      for (int j = 0; j < 4; ++j)
        bfr[j] = *(const bf16x8*)&sB[(wn * 64 + j * 16 + fr) * 32 + fq];
#pragma unroll
      for (int i = 0; i < 4; ++i)
#pragma unroll
        for (int j = 0; j < 4; ++j)
          acc[i][j] = __builtin_amdgcn_mfma_f32_16x16x32_bf16(
              af[i], bfr[j], acc[i][j], 0, 0, 0);
    }
    __syncthreads();
  }

  // C/D layout (m89-verified): col = lane&15, row = (lane>>4)*4 + reg
  const int fr = lane & 15, fq4 = (lane >> 4) << 2;
#pragma unroll
  for (int i = 0; i < 4; ++i) {
#pragma unroll
    for (int j = 0; j < 4; ++j) {
      const int rbase = row0 + wm * 64 + i * 16 + fq4;
      const int col = col0 + wn * 64 + j * 16 + fr;
      if constexpr (EPI == 5) {
        const int b = rbase >> 11, t = rbase & 2047;
        const int hh = col >> 6, d = col & 63;
        bf16x4 o4 = {(bf16)acc[i][j][0], (bf16)acc[i][j][1],
                     (bf16)acc[i][j][2], (bf16)acc[i][j][3]};
        *(bf16x4*)&((bf16*)Cv)[(((size_t)(b * 16 + hh)) * 64 + d) * 2048 + t] =
            o4;
      } else {
#pragma unroll
        for (int r = 0; r < 4; ++r) {
          const size_t idx = (size_t)(rbase + r) * N + col;
          const float val = acc[i][j][r];
          if constexpr (EPI == 0) {
            ((float*)Cv)[idx] = val;
          } else if constexpr (EPI == 2) {
            ((float*)Cv)[idx] = val + R[idx];
          } else {  // EPI == 3
            ((bf16*)Cv)[idx] =
                (bf16)(0.5f * val * (1.0f + erff(val * 0.7071067811865476f)));
          }
        }
      }
    }
  }
}

// ---------------------------------------------------------------------------
// Merged split-K GEMM for q/k (BK=64, two sub-steps per barrier): stages
// A_hi, A_lo AND B each k-step (B loaded ONCE). Split bf16 hi/lo epilogue.
// ---------------------------------------------------------------------------
static __device__ __forceinline__ void gemm_split_merged(
    const bf16* __restrict__ A, const bf16* __restrict__ A2,
    const bf16* __restrict__ B, bf16* __restrict__ Chi, bf16* __restrict__ Clo,
    bf16* smem, float scale, int col0, int row0) {
  constexpr int K = 1024, N = 1024;
  bf16* sAh0 = smem;           // 128 x 32
  bf16* sAh1 = smem + 4096;    // k+32
  bf16* sAl0 = smem + 8192;
  bf16* sAl1 = smem + 12288;
  bf16* sB0 = smem + 16384;
  bf16* sB1 = smem + 20480;
  const int tid = threadIdx.x;
  const int lane = tid & 63;
  const int wid = tid >> 6;
  const int wm = wid >> 1, wn = wid & 1;

  f32x4 acc[4][4];
  const f32x4 fzero = {0.f, 0.f, 0.f, 0.f};
#pragma unroll
  for (int i = 0; i < 4; ++i)
#pragma unroll
    for (int j = 0; j < 4; ++j) acc[i][j] = fzero;

  const int r0 = tid >> 2, c0 = (tid & 3) << 3;
  const int r1 = (256 + tid) >> 2, c1 = ((256 + tid) & 3) << 3;
  const int wofs0 = (wid << 6) * 8;
  const int wofs1 = (256 + (wid << 6)) * 8;

  for (int kt = 0; kt < 16; ++kt) {
    const int k0 = kt << 6;
    async16(A + (size_t)(row0 + r0) * K + k0 + c0, sAh0 + wofs0);
    async16(A + (size_t)(row0 + r1) * K + k0 + c1, sAh0 + wofs1);
    async16(A + (size_t)(row0 + r0) * K + k0 + 32 + c0, sAh1 + wofs0);
    async16(A + (size_t)(row0 + r1) * K + k0 + 32 + c1, sAh1 + wofs1);
    async16(A2 + (size_t)(row0 + r0) * K + k0 + c0, sAl0 + wofs0);
    async16(A2 + (size_t)(row0 + r1) * K + k0 + c1, sAl0 + wofs1);
    async16(A2 + (size_t)(row0 + r0) * K + k0 + 32 + c0, sAl1 + wofs0);
    async16(A2 + (size_t)(row0 + r1) * K + k0 + 32 + c1, sAl1 + wofs1);
    async16(B + (size_t)(col0 + r0) * K + k0 + c0, sB0 + wofs0);
    async16(B + (size_t)(col0 + r1) * K + k0 + c1, sB0 + wofs1);
    async16(B + (size_t)(col0 + r0) * K + k0 + 32 + c0, sB1 + wofs0);
    async16(B + (size_t)(col0 + r1) * K + k0 + 32 + c1, sB1 + wofs1);
    __syncthreads();
    const int fr = lane & 15, fq = (lane >> 4) << 3;
#pragma unroll
    for (int t = 0; t < 2; ++t) {
      const bf16* sAh = t ? sAh1 : sAh0;
      const bf16* sAl = t ? sAl1 : sAl0;
      const bf16* sB = t ? sB1 : sB0;
      bf16x8 ah[4], al[4], bfr[4];
#pragma unroll
      for (int i = 0; i < 4; ++i) {
        ah[i] = *(const bf16x8*)&sAh[(wm * 64 + i * 16 + fr) * 32 + fq];
        al[i] = *(const bf16x8*)&sAl[(wm * 64 + i * 16 + fr) * 32 + fq];
      }
#pragma unroll
      for (int j = 0; j < 4; ++j)
        bfr[j] = *(const bf16x8*)&sB[(wn * 64 + j * 16 + fr) * 32 + fq];
#pragma unroll
      for (int i = 0; i < 4; ++i)
#pragma unroll
        for (int j = 0; j < 4; ++j) {
          acc[i][j] = __builtin_amdgcn_mfma_f32_16x16x32_bf16(
              ah[i], bfr[j], acc[i][j], 0, 0, 0);
          acc[i][j] = __builtin_amdgcn_mfma_f32_16x16x32_bf16(
              al[i], bfr[j], acc[i][j], 0, 0, 0);
        }
    }
    __syncthreads();
  }

  const int fr = lane & 15, fq4 = (lane >> 4) << 2;
#pragma unroll
  for (int i = 0; i < 4; ++i)
#pragma unroll
    for (int j = 0; j < 4; ++j) {
      const int rbase = row0 + wm * 64 + i * 16 + fq4;
      const int col = col0 + wn * 64 + j * 16 + fr;
#pragma unroll
      for (int r = 0; r < 4; ++r) {
        const size_t idx = (size_t)(rbase + r) * N + col;
        const float vs = acc[i][j][r] * scale;
        const bf16 hi = (bf16)vs;
        Chi[idx] = hi;
        Clo[idx] = (bf16)(vs - (float)hi);
      }
    }
}

// Q,K,V fused: grid (24, 32). bx>>3: 0=q (merged split, scale folds 1/8 AND
// log2e for the exp2 softmax), 1=k (merged split), 2=v (single-pass bf16 h,
// transposed store). ONE shared buffer (49152 B) for both paths.
__global__ __launch_bounds__(256) void gemm_qkv(
    const bf16* __restrict__ A, const bf16* __restrict__ A2,
    const bf16* __restrict__ Bq, const bf16* __restrict__ Bk,
    const bf16* __restrict__ Bv, bf16* qh, bf16* ql, bf16* kh, bf16* kl,
    bf16* vt) {
  __shared__ bf16 smem[24576];
  const int which = blockIdx.x >> 3;
  const int col0 = (blockIdx.x & 7) * 128, row0 = blockIdx.y * 128;
  if (which == 2) {
    gemm_body<5>(A, Bv, (void*)vt, nullptr, smem, col0, row0, 4096, 1024,
                 1024);
  } else {
    gemm_split_merged(A, A2, which ? Bk : Bq, which ? kh : qh, which ? kl : ql,
                      smem, which ? 1.0f : 0.125f * 1.44269504088896f, col0,
                      row0);
  }
}

// ---------------------------------------------------------------------------
// 128x64-tile GEMM, BK=128 as FOUR BK=32 sub-buffers per barrier pair.
// acc[4][2] = 32 AGPR -> more waves/SIMD; half the barrier drains per K;
// 2x blocks for residency. r1/r3 evidence: Wo, FF1, FF2 all improved here.
// EPI: 0 = f32, 2 = f32(acc+R), 3 = bf16 gelu(acc).
// ---------------------------------------------------------------------------
template <int EPI>
__global__ __launch_bounds__(256) void gemm_bt64(
    const bf16* __restrict__ A, const bf16* __restrict__ B,
    void* __restrict__ Cv, const float* __restrict__ R, int M, int N, int K) {
  __shared__ bf16 smem[24576];  // A: 4 x (128x32) = 16384; B: 4 x (64x32) = 8192
  const int col0 = blockIdx.x * 64, row0 = blockIdx.y * 128;
  const int tid = threadIdx.x;
  const int lane = tid & 63;
  const int wid = tid >> 6;
  const int wm = wid >> 1, wn = wid & 1;

  f32x4 acc[4][2];
  const f32x4 fzero = {0.f, 0.f, 0.f, 0.f};
#pragma unroll
  for (int i = 0; i < 4; ++i)
#pragma unroll
    for (int j = 0; j < 2; ++j) acc[i][j] = fzero;

  const int nk = K >> 7;
  const int r0 = tid >> 2, c0 = (tid & 3) << 3;
  const int r1 = (256 + tid) >> 2, c1 = ((256 + tid) & 3) << 3;
  const int wofs0 = (wid << 6) * 8;
  const int wofs1 = (256 + (wid << 6)) * 8;

  for (int kt = 0; kt < nk; ++kt) {
    const int k0 = kt << 7;
#pragma unroll
    for (int t = 0; t < 4; ++t) {
      bf16* sA = smem + t * 4096;
      bf16* sB = smem + 16384 + t * 2048;
      async16(A + (size_t)(row0 + r0) * K + k0 + t * 32 + c0, sA + wofs0);
      async16(A + (size_t)(row0 + r1) * K + k0 + t * 32 + c1, sA + wofs1);
      async16(B + (size_t)(col0 + r0) * K + k0 + t * 32 + c0, sB + wofs0);
    }
    __syncthreads();
    const int fr = lane & 15, fq = (lane >> 4) << 3;
#pragma unroll
    for (int t = 0; t < 4; ++t) {
      const bf16* sA = smem + t * 4096;
      const bf16* sB = smem + 16384 + t * 2048;
      bf16x8 af[4], bfr[2];
#pragma unroll
      for (int i = 0; i < 4; ++i)
        af[i] = *(const bf16x8*)&sA[(wm * 64 + i * 16 + fr) * 32 + fq];
#pragma unroll
      for (int j = 0; j < 2; ++j)
        bfr[j] = *(const bf16x8*)&sB[(wn * 32 + j * 16 + fr) * 32 + fq];
#pragma unroll
      for (int i = 0; i < 4; ++i)
#pragma unroll
        for (int j = 0; j < 2; ++j)
          acc[i][j] = __builtin_amdgcn_mfma_f32_16x16x32_bf16(
              af[i], bfr[j], acc[i][j], 0, 0, 0);
    }
    __syncthreads();
  }

  const int fr = lane & 15, fq4 = (lane >> 4) << 2;
#pragma unroll
  for (int i = 0; i < 4; ++i) {
#pragma unroll
    for (int j = 0; j < 2; ++j) {
      const int rbase = row0 + wm * 64 + i * 16 + fq4;
      const int col = col0 + wn * 32 + j * 16 + fr;
#pragma unroll
      for (int r = 0; r < 4; ++r) {
        const size_t idx = (size_t)(rbase + r) * N + col;
        const float val = acc[i][j][r];
        if constexpr (EPI == 3) {
          ((bf16*)Cv)[idx] =
              (bf16)(0.5f * val * (1.0f + erff(val * 0.7071067811865476f)));
        } else if constexpr (EPI == 2) {
          ((float*)Cv)[idx] = val + R[idx];
        } else {
          ((float*)Cv)[idx] = val;
        }
      }
    }
  }
}

// ---------------------------------------------------------------------------
// MFMA causal flash attention (64-query blocks) fused with cvt2
// (FF weights f32->bf16) in blocks [1024, 9216).
//  - logits in log2 domain (log2e folded into q scale) -> exp2f softmax
//  - Q fragments from global; next K/V tile register-prefetched
//  - 2 barriers/iter; P tile wave-private (stride 76, intra-wave RAW only)
//  - DPP rowmax softmax; LDS 37376 B -> 4 blocks/CU
//  - r1 POST-MORTEM: T5 setprio + T13 defer-rescale REGRESSED. DO NOT re-add.
//  - r2 (kept): band bh pinned to XCD = bid&7 (3 MB K/V set, L2-resident).
//  - r4 NEW (a): l = sum(P) via 2 extra MFMAs with B=ones (l4 acc, D-layout
//    row-sum replicated over lanes) — removes rowsum16 DPP chains (~96
//    VALU cyc/wave-iter). l now sums the same bf16 P that PV consumes.
//  - r4 NEW (b): balanced qt pairing. Round-robin placement gives CU slot
//    u = bid&255 for all 4 resident sets s = bid>>8; qt = s odd ? q0 : 31-q0
//    makes every CU total exactly 66 tile-iters (was 52..80).
//  - plain __launch_bounds__(256): (256,4) caused scratch spill — keep off
// ---------------------------------------------------------------------------
__global__ __launch_bounds__(256) void attn_cvt2(
    const bf16* __restrict__ qh_g, const bf16* __restrict__ ql_g,
    const bf16* __restrict__ kh_g, const bf16* __restrict__ kl_g,
    const bf16* __restrict__ vt_g, bf16* __restrict__ out,
    const float* __restrict__ Wf1, const float* __restrict__ Wf2,
    bf16* __restrict__ wdst) {
  __shared__ bf16 lds[18688];  // 37376 B
  const int tid = threadIdx.x;
  if (blockIdx.x >= 1024) {  // cvt2 path
    const size_t i = ((size_t)(blockIdx.x - 1024) * 256 + tid) * 4;
    const size_t M4 = 4u << 20;
    const float* src = (i < M4) ? Wf1 : Wf2;
    const size_t off = (i < M4) ? i : i - M4;
    const float4 v = *(const float4*)(src + off);
    bf16x4 o4 = {(bf16)v.x, (bf16)v.y, (bf16)v.z, (bf16)v.w};
    *(bf16x4*)(wdst + i) = o4;
    return;
  }
  bf16* Kh = lds;          // 64 x 72
  bf16* Kl = lds + 4608;   // 64 x 72
  bf16* Vt = lds + 9216;   // 64 x 72, rows = dim d, cols = key
  bf16* Ps = lds + 13824;  // 4 waves x 16 x 76 (wave-private)

  const int bid = blockIdx.x;
  // Balanced remap (bijective on [0,1024)): u = CU slot, s = resident set.
  const int u = bid & 255;
  const int s = bid >> 8;               // 0..3
  const int q0 = u >> 3;                // 0..31
  const int qt = (s & 1) ? q0 : 31 - q0;
  const int bh = (u & 7) * 4 + s;       // band pinned to XCD = bid&7
  const int h = bh & 15;
  const int b = bh >> 4;
  const int t0 = qt << 6;
  const int w = tid >> 6;
  const int lane = tid & 63;
  const int c = lane & 15;
  const int quad = lane >> 4;

  const int r0 = tid >> 3, c0 = (tid & 7) << 3;
  const int r1 = (tid + 256) >> 3, c1 = ((tid + 256) & 7) << 3;

  // Q fragments straight from global (once per block)
  const size_t qrow =
      ((size_t)(b * 2048 + t0 + w * 16 + c)) * 1024 + h * 64 + quad * 8;
  bf16x8 aqh[2], aql[2];
  aqh[0] = *(const bf16x8*)&qh_g[qrow];
  aqh[1] = *(const bf16x8*)&qh_g[qrow + 32];
  aql[0] = *(const bf16x8*)&ql_g[qrow];
  aql[1] = *(const bf16x8*)&ql_g[qrow + 32];

  f32x4 o[4];
  const f32x4 fzero = {0.f, 0.f, 0.f, 0.f};
#pragma unroll
  for (int j = 0; j < 4; ++j) o[j] = fzero;
  f32x4 l4 = fzero;  // row-sum accumulator (MFMA with B=ones)
  float m_i[4] = {-3e38f, -3e38f, -3e38f, -3e38f};

  bf16x8 vone;
#pragma unroll
  for (int z = 0; z < 8; ++z) vone[z] = (bf16)1.0f;

  const size_t vtb = ((size_t)(b * 16 + h)) * 64 * 2048;  // + d*2048 + t
  const size_t kband = ((size_t)(b * 2048)) * 1024 + h * 64;

  bf16x8 gk[6];  // register prefetch of next K/V tile
  {
    gk[0] = *(const bf16x8*)&kh_g[kband + (size_t)r0 * 1024 + c0];
    gk[1] = *(const bf16x8*)&kh_g[kband + (size_t)r1 * 1024 + c1];
    gk[2] = *(const bf16x8*)&kl_g[kband + (size_t)r0 * 1024 + c0];
    gk[3] = *(const bf16x8*)&kl_g[kband + (size_t)r1 * 1024 + c1];
    gk[4] = *(const bf16x8*)&vt_g[vtb + (size_t)r0 * 2048 + c0];
    gk[5] = *(const bf16x8*)&vt_g[vtb + (size_t)r1 * 2048 + c1];
  }

  for (int kt = 0; kt <= qt; ++kt) {
    __syncthreads();  // (A) prev tile's fragment reads done before restage
    *(bf16x8*)&Kh[r0 * 72 + c0] = gk[0];
    *(bf16x8*)&Kh[r1 * 72 + c1] = gk[1];
    *(bf16x8*)&Kl[r0 * 72 + c0] = gk[2];
    *(bf16x8*)&Kl[r1 * 72 + c1] = gk[3];
    *(bf16x8*)&Vt[r0 * 72 + c0] = gk[4];
    *(bf16x8*)&Vt[r1 * 72 + c1] = gk[5];
    __syncthreads();  // (B) staging visible

    if (kt < qt) {  // prefetch next tile; latency hidden behind compute
      const int kb1 = (kt + 1) << 6;
      const size_t kbase = kband + (size_t)kb1 * 1024;
      gk[0] = *(const bf16x8*)&kh_g[kbase + (size_t)r0 * 1024 + c0];
      gk[1] = *(const bf16x8*)&kh_g[kbase + (size_t)r1 * 1024 + c1];
      gk[2] = *(const bf16x8*)&kl_g[kbase + (size_t)r0 * 1024 + c0];
      gk[3] = *(const bf16x8*)&kl_g[kbase + (size_t)r1 * 1024 + c1];
      gk[4] = *(const bf16x8*)&vt_g[vtb + (size_t)r0 * 2048 + kb1 + c0];
      gk[5] = *(const bf16x8*)&vt_g[vtb + (size_t)r1 * 2048 + kb1 + c1];
    }

    bf16x8 bkh[4][2], bkl[4][2];
#pragma unroll
    for (int j = 0; j < 4; ++j)
#pragma unroll
      for (int s2 = 0; s2 < 2; ++s2) {
        bkh[j][s2] = *(const bf16x8*)&Kh[(j * 16 + c) * 72 + s2 * 32 + quad * 8];
        bkl[j][s2] = *(const bf16x8*)&Kl[(j * 16 + c) * 72 + s2 * 32 + quad * 8];
      }

    f32x4 s4[4];
#pragma unroll
    for (int j = 0; j < 4; ++j) s4[j] = fzero;
#pragma unroll
    for (int j = 0; j < 4; ++j)
#pragma unroll
      for (int s2 = 0; s2 < 2; ++s2) {
        s4[j] = __builtin_amdgcn_mfma_f32_16x16x32_bf16(aqh[s2], bkh[j][s2], s4[j], 0, 0, 0);
        s4[j] = __builtin_amdgcn_mfma_f32_16x16x32_bf16(aqh[s2], bkl[j][s2], s4[j], 0, 0, 0);
        s4[j] = __builtin_amdgcn_mfma_f32_16x16x32_bf16(aql[s2], bkh[j][s2], s4[j], 0, 0, 0);
      }

    if (kt == qt) {  // diagonal tile: strict-upper mask (t0 == kb)
#pragma unroll
      for (int j = 0; j < 4; ++j)
#pragma unroll
        for (int r = 0; r < 4; ++r)
          if (j * 16 + c > w * 16 + quad * 4 + r) s4[j][r] = -3e38f;
    }

    float p[4][4];
#pragma unroll
    for (int r = 0; r < 4; ++r) {
      float mt = fmaxf(fmaxf(s4[0][r], s4[1][r]), fmaxf(s4[2][r], s4[3][r]));
      mt = rowmax16(mt);  // DPP row reduce
      const float mn = fmaxf(m_i[r], mt);
      const float al = exp2f(m_i[r] - mn);  // logits already in log2 domain
      m_i[r] = mn;
#pragma unroll
      for (int j = 0; j < 4; ++j) p[r][j] = exp2f(s4[j][r] - mn);
      l4[r] *= al;
#pragma unroll
      for (int j = 0; j < 4; ++j) o[j][r] *= al;
    }

    // P -> wave-private region, stride 76 (conflict-free; intra-wave RAW only)
    bf16* Pw = Ps + w * 16 * 76;
#pragma unroll
    for (int r = 0; r < 4; ++r)
#pragma unroll
      for (int j = 0; j < 4; ++j)
        Pw[(quad * 4 + r) * 76 + j * 16 + c] = (bf16)p[r][j];

    bf16x8 ap[2], bv[4][2];
#pragma unroll
    for (int s2 = 0; s2 < 2; ++s2)
      ap[s2] = *(const bf16x8*)&Pw[c * 76 + s2 * 32 + quad * 8];
#pragma unroll
    for (int j = 0; j < 4; ++j)
#pragma unroll
      for (int s2 = 0; s2 < 2; ++s2)
        bv[j][s2] = *(const bf16x8*)&Vt[(j * 16 + c) * 72 + s2 * 32 + quad * 8];
    // l row-sum via MFMA (B = ones): D[m][n] = sum_k P[m][k], all n equal.
    l4 = __builtin_amdgcn_mfma_f32_16x16x32_bf16(ap[0], vone, l4, 0, 0, 0);
    l4 = __builtin_amdgcn_mfma_f32_16x16x32_bf16(ap[1], vone, l4, 0, 0, 0);
#pragma unroll
    for (int j = 0; j < 4; ++j)
#pragma unroll
      for (int s2 = 0; s2 < 2; ++s2)
        o[j] = __builtin_amdgcn_mfma_f32_16x16x32_bf16(ap[s2], bv[j][s2], o[j], 0, 0, 0);
  }

#pragma unroll
  for (int r = 0; r < 4; ++r) {
    const float inv = 1.0f / l4[r];
#pragma unroll
    for (int j = 0; j < 4; ++j) {
      const size_t oi =
          ((size_t)(b * 2048 + t0 + w * 16 + quad * 4 + r)) * 1024 + h * 64 +
          j * 16 + c;
      out[oi] = (bf16)(o[j][r] * inv);
    }
  }
}

// ---------------------------------------------------------------------------
// Workspace plan (80 MiB peak; >104 MiB previously corrupted harness memory):
//   [ 0, 8)   Wq|Wk|Wv|Wo bf16
//   [ 8,24)   h_hi|h_lo  -> (after gemm_qkv) Wf1_b|Wf2_b   (attn_cvt2 fills)
//   [24,40)   qh|ql      -> (after attn)   x1 (f32)
//   [40,72)   kh|kl|vt|attnout -> (after Wo) ff (bf16 4096x4096)
//   [72,80)   h2
// ---------------------------------------------------------------------------
extern "C" void kernel_launch(void* const* d_in, const int* in_sizes, int n_in,
                              void* d_out, int out_size, void* d_ws,
                              size_t ws_size, hipStream_t stream) {
  const float* x = (const float*)d_in[0];
  const float* g1 = (const float*)d_in[2];
  const float* b1 = (const float*)d_in[3];
  const float* g2 = (const float*)d_in[4];
  const float* b2 = (const float*)d_in[5];
  const float* Wq = (const float*)d_in[6];
  const float* Wk = (const float*)d_in[7];
  const float* Wv = (const float*)d_in[8];
  const float* Wo = (const float*)d_in[9];
  const float* Wf1 = (const float*)d_in[10];
  const float* Wf2 = (const float*)d_in[11];
  char* ws = (char*)d_ws;
  const size_t MB = 1024 * 1024;
  const size_t M1 = 1u << 20;
  bf16* Wq_b = (bf16*)ws;
  bf16* Wk_b = Wq_b + 1 * M1;
  bf16* Wv_b = Wq_b + 2 * M1;
  bf16* Wo_b = Wq_b + 3 * M1;
  bf16* h_hi = (bf16*)(ws + 8 * MB);
  bf16* h_lo = (bf16*)(ws + 16 * MB);
  bf16* Wf1_b = h_hi;  // alias: h dead after gemm_qkv; attn_cvt2 fills
  bf16* Wf2_b = h_lo;
  bf16* qh = (bf16*)(ws + 24 * MB);
  bf16* ql = (bf16*)(ws + 32 * MB);
  bf16* kh = (bf16*)(ws + 40 * MB);
  bf16* kl = (bf16*)(ws + 48 * MB);
  bf16* vt = (bf16*)(ws + 56 * MB);
  bf16* attnout = (bf16*)(ws + 64 * MB);
  float* x1 = (float*)qh;  // alias: qh/ql dead after attn
  bf16* h2 = (bf16*)(ws + 72 * MB);
  bf16* ff = kh;  // alias: kh/kl/vt/attnout dead after Wo GEMM
  float* outp = (float*)d_out;

  // 1) LN1 (split bf16 hi/lo) + cvt4 (attention weights) in one launch
  ln1_cvt4<<<8192, 256, 0, stream>>>(x, g1, b1, h_hi, h_lo, Wq, Wk, Wv, Wo,
                                     Wq_b);
  // 2) Q,K (merged split bf16, q scale = 1/8*log2e) + V^T fused
  gemm_qkv<<<dim3(24, 32), 256, 0, stream>>>(h_hi, h_lo, Wq_b, Wk_b, Wv_b, qh,
                                             ql, kh, kl, vt);
  // 3) attention (blocks 0..1023) + cvt2 FF weights (blocks 1024..9215)
  attn_cvt2<<<9216, 256, 0, stream>>>(qh, ql, kh, kl, vt, attnout, Wf1, Wf2,
                                      Wf1_b);
  // 4) x1 = x + attnout @ Wo^T   (f32; overwrites dead qh/ql) — 64N tiles
  gemm_bt64<2><<<dim3(16, 32), 256, 0, stream>>>(attnout, Wo_b, (void*)x1, x,
                                                 4096, 1024, 1024);
  // 5) LN2 -> h2 (bf16)
  ln_kernel<<<4096, 256, 0, stream>>>(x1, g2, b2, h2);
  // 6) ff = gelu(h2 @ Wff1^T)  (bf16; 128x64 tiles, BK=128)
  gemm_bt64<3><<<dim3(64, 32), 256, 0, stream>>>(h2, Wf1_b, (void*)ff, nullptr,
                                                 4096, 4096, 1024);
  // 7) out = x1 + ff @ Wff2^T  (f32) — 64N tiles
  gemm_bt64<2><<<dim3(16, 32), 256, 0, stream>>>(ff, Wf2_b, (void*)outp, x1,
                                                 4096, 1024, 4096);
}

// Round 6
// 408.614 us; speedup vs baseline: 1.0195x; 1.0195x over previous
//
#include <hip/hip_runtime.h>

typedef __bf16 bf16;
typedef bf16 bf16x8 __attribute__((ext_vector_type(8)));
typedef bf16 bf16x4 __attribute__((ext_vector_type(4)));
typedef float f32x4 __attribute__((ext_vector_type(4)));

// ---------------------------------------------------------------------------
// async global->LDS 16B copy (wave-uniform LDS base + lane*16 placement)
// ---------------------------------------------------------------------------
static __device__ __forceinline__ void async16(const void* g, void* l) {
  __builtin_amdgcn_global_load_lds((__attribute__((address_space(1))) void*)g,
                                   (__attribute__((address_space(3))) void*)l,
                                   16, 0, 0);
}

// DPP row_ror:N within 16-lane rows (VALU-only cross-lane; no LDS pipe).
template <int N>
static __device__ __forceinline__ float ror16(float x) {
  const int y =
      __builtin_amdgcn_update_dpp(0, __float_as_int(x), 0x120 | N, 0xf, 0xf, true);
  return __int_as_float(y);
}
static __device__ __forceinline__ float rowmax16(float x) {
  x = fmaxf(x, ror16<8>(x));
  x = fmaxf(x, ror16<4>(x));
  x = fmaxf(x, ror16<2>(x));
  x = fmaxf(x, ror16<1>(x));
  return x;
}

// ---------------------------------------------------------------------------
// LN1 (split bf16 hi/lo) fused with cvt4 (attention weights f32->bf16).
// blocks [0,4096): LN rows; blocks [4096,8192): weight conversion chunks.
// ---------------------------------------------------------------------------
__global__ __launch_bounds__(256) void ln1_cvt4(
    const float* __restrict__ x, const float* __restrict__ g,
    const float* __restrict__ b, bf16* __restrict__ hi, bf16* __restrict__ lo,
    const float* __restrict__ Wq, const float* __restrict__ Wk,
    const float* __restrict__ Wv, const float* __restrict__ Wo,
    bf16* __restrict__ wdst) {
  const int tid = threadIdx.x;
  if (blockIdx.x >= 4096) {  // cvt4 path
    const size_t i = ((size_t)(blockIdx.x - 4096) * 256 + tid) * 4;
    const size_t M1 = 1u << 20;
    const float* src = (i < M1) ? Wq : (i < 2 * M1) ? Wk : (i < 3 * M1) ? Wv : Wo;
    const size_t off = i & (M1 - 1);
    const float4 v = *(const float4*)(src + off);
    bf16x4 o = {(bf16)v.x, (bf16)v.y, (bf16)v.z, (bf16)v.w};
    *(bf16x4*)(wdst + i) = o;
    return;
  }
  const int row = blockIdx.x;
  const float* xr = x + (size_t)row * 1024;
  float v[4];
  float s1 = 0.f, s2 = 0.f;
#pragma unroll
  for (int j = 0; j < 4; ++j) {
    v[j] = xr[j * 256 + tid];
    s1 += v[j];
    s2 += v[j] * v[j];
  }
#pragma unroll
  for (int off = 1; off < 64; off <<= 1) {
    s1 += __shfl_xor(s1, off);
    s2 += __shfl_xor(s2, off);
  }
  __shared__ float ws1[4], ws2[4];
  const int wid = tid >> 6;
  if ((tid & 63) == 0) {
    ws1[wid] = s1;
    ws2[wid] = s2;
  }
  __syncthreads();
  s1 = ws1[0] + ws1[1] + ws1[2] + ws1[3];
  s2 = ws2[0] + ws2[1] + ws2[2] + ws2[3];
  const float mu = s1 * (1.f / 1024.f);
  const float var = s2 * (1.f / 1024.f) - mu * mu;
  const float rstd = 1.0f / sqrtf(var + 1e-5f);
#pragma unroll
  for (int j = 0; j < 4; ++j) {
    const int cc = j * 256 + tid;
    const float y = (v[j] - mu) * rstd * g[cc] + b[cc];
    const bf16 yh = (bf16)y;
    hi[(size_t)row * 1024 + cc] = yh;
    lo[(size_t)row * 1024 + cc] = (bf16)(y - (float)yh);
  }
}

// ---------------------------------------------------------------------------
// LayerNorm over D=1024 (f32 input), one block per row (non-split).
// ---------------------------------------------------------------------------
__global__ __launch_bounds__(256) void ln_kernel(
    const float* __restrict__ x, const float* __restrict__ g,
    const float* __restrict__ b, bf16* __restrict__ hi) {
  const int row = blockIdx.x;
  const int tid = threadIdx.x;
  const float* xr = x + (size_t)row * 1024;
  float v[4];
  float s1 = 0.f, s2 = 0.f;
#pragma unroll
  for (int j = 0; j < 4; ++j) {
    v[j] = xr[j * 256 + tid];
    s1 += v[j];
    s2 += v[j] * v[j];
  }
#pragma unroll
  for (int off = 1; off < 64; off <<= 1) {
    s1 += __shfl_xor(s1, off);
    s2 += __shfl_xor(s2, off);
  }
  __shared__ float ws1[4], ws2[4];
  const int wid = tid >> 6;
  if ((tid & 63) == 0) {
    ws1[wid] = s1;
    ws2[wid] = s2;
  }
  __syncthreads();
  s1 = ws1[0] + ws1[1] + ws1[2] + ws1[3];
  s2 = ws2[0] + ws2[1] + ws2[2] + ws2[3];
  const float mu = s1 * (1.f / 1024.f);
  const float var = s2 * (1.f / 1024.f) - mu * mu;
  const float rstd = 1.0f / sqrtf(var + 1e-5f);
#pragma unroll
  for (int j = 0; j < 4; ++j) {
    const int cc = j * 256 + tid;
    const float y = (v[j] - mu) * rstd * g[cc] + b[cc];
    hi[(size_t)row * 1024 + cc] = (bf16)y;
  }
}

// ---------------------------------------------------------------------------
// GEMM body: C[M,N] = A[M,K] * B[N,K]^T   (m97 structure, BK=64 as two BK=32
// sub-buffers per barrier pair). Used by gemm_qkv (EPI=5 V^T path).
// ---------------------------------------------------------------------------
template <int EPI>
static __device__ __forceinline__ void gemm_body(
    const bf16* __restrict__ A, const bf16* __restrict__ B,
    void* __restrict__ Cv, const float* __restrict__ R, bf16* smem, int col0,
    int row0, int M, int N, int K) {
  bf16* sA0 = smem;          // 128 x 32
  bf16* sA1 = smem + 4096;   // 128 x 32 (k+32)
  bf16* sB0 = smem + 8192;   // 128 x 32
  bf16* sB1 = smem + 12288;  // 128 x 32 (k+32)
  const int tid = threadIdx.x;
  const int lane = tid & 63;
  const int wid = tid >> 6;
  const int wm = wid >> 1, wn = wid & 1;

  f32x4 acc[4][4];
  const f32x4 fzero = {0.f, 0.f, 0.f, 0.f};
#pragma unroll
  for (int i = 0; i < 4; ++i)
#pragma unroll
    for (int j = 0; j < 4; ++j) acc[i][j] = fzero;

  const int nk = K >> 6;
  const int r0 = tid >> 2, c0 = (tid & 3) << 3;
  const int r1 = (256 + tid) >> 2, c1 = ((256 + tid) & 3) << 3;
  const int wofs0 = (wid << 6) * 8;  // wave-uniform LDS offsets
  const int wofs1 = (256 + (wid << 6)) * 8;

  for (int kt = 0; kt < nk; ++kt) {
    const int k0 = kt << 6;
    async16(A + (size_t)(row0 + r0) * K + k0 + c0, sA0 + wofs0);
    async16(A + (size_t)(row0 + r1) * K + k0 + c1, sA0 + wofs1);
    async16(A + (size_t)(row0 + r0) * K + k0 + 32 + c0, sA1 + wofs0);
    async16(A + (size_t)(row0 + r1) * K + k0 + 32 + c1, sA1 + wofs1);
    async16(B + (size_t)(col0 + r0) * K + k0 + c0, sB0 + wofs0);
    async16(B + (size_t)(col0 + r1) * K + k0 + c1, sB0 + wofs1);
    async16(B + (size_t)(col0 + r0) * K + k0 + 32 + c0, sB1 + wofs0);
    async16(B + (size_t)(col0 + r1) * K + k0 + 32 + c1, sB1 + wofs1);
    __syncthreads();
    const int fr = lane & 15, fq = (lane >> 4) << 3;
#pragma unroll
    for (int t = 0; t < 2; ++t) {
      const bf16* sA = t ? sA1 : sA0;
      const bf16* sB = t ? sB1 : sB0;
      bf16x8 af[4], bfr[4];
#pragma unroll
      for (int i = 0; i < 4; ++i)
        af[i] = *(const bf16x8*)&sA[(wm * 64 + i * 16 + fr) * 32 + fq];
#pragma unroll
      for (int j = 0; j < 4; ++j)
        bfr[j] = *(const bf16x8*)&sB[(wn * 64 + j * 16 + fr) * 32 + fq];
#pragma unroll
      for (int i = 0; i < 4; ++i)
#pragma unroll
        for (int j = 0; j < 4; ++j)
          acc[i][j] = __builtin_amdgcn_mfma_f32_16x16x32_bf16(
              af[i], bfr[j], acc[i][j], 0, 0, 0);
    }
    __syncthreads();
  }

  // C/D layout (m89-verified): col = lane&15, row = (lane>>4)*4 + reg
  const int fr = lane & 15, fq4 = (lane >> 4) << 2;
#pragma unroll
  for (int i = 0; i < 4; ++i) {
#pragma unroll
    for (int j = 0; j < 4; ++j) {
      const int rbase = row0 + wm * 64 + i * 16 + fq4;
      const int col = col0 + wn * 64 + j * 16 + fr;
      if constexpr (EPI == 5) {
        const int b = rbase >> 11, t = rbase & 2047;
        const int hh = col >> 6, d = col & 63;
        bf16x4 o4 = {(bf16)acc[i][j][0], (bf16)acc[i][j][1],
                     (bf16)acc[i][j][2], (bf16)acc[i][j][3]};
        *(bf16x4*)&((bf16*)Cv)[(((size_t)(b * 16 + hh)) * 64 + d) * 2048 + t] =
            o4;
      } else {
#pragma unroll
        for (int r = 0; r < 4; ++r) {
          const size_t idx = (size_t)(rbase + r) * N + col;
          const float val = acc[i][j][r];
          if constexpr (EPI == 0) {
            ((float*)Cv)[idx] = val;
          } else if constexpr (EPI == 2) {
            ((float*)Cv)[idx] = val + R[idx];
          } else {  // EPI == 3
            ((bf16*)Cv)[idx] =
                (bf16)(0.5f * val * (1.0f + erff(val * 0.7071067811865476f)));
          }
        }
      }
    }
  }
}

// ---------------------------------------------------------------------------
// Merged split-K GEMM for q/k (BK=64, two sub-steps per barrier): stages
// A_hi, A_lo AND B each k-step (B loaded ONCE). Split bf16 hi/lo epilogue.
// ---------------------------------------------------------------------------
static __device__ __forceinline__ void gemm_split_merged(
    const bf16* __restrict__ A, const bf16* __restrict__ A2,
    const bf16* __restrict__ B, bf16* __restrict__ Chi, bf16* __restrict__ Clo,
    bf16* smem, float scale, int col0, int row0) {
  constexpr int K = 1024, N = 1024;
  bf16* sAh0 = smem;           // 128 x 32
  bf16* sAh1 = smem + 4096;    // k+32
  bf16* sAl0 = smem + 8192;
  bf16* sAl1 = smem + 12288;
  bf16* sB0 = smem + 16384;
  bf16* sB1 = smem + 20480;
  const int tid = threadIdx.x;
  const int lane = tid & 63;
  const int wid = tid >> 6;
  const int wm = wid >> 1, wn = wid & 1;

  f32x4 acc[4][4];
  const f32x4 fzero = {0.f, 0.f, 0.f, 0.f};
#pragma unroll
  for (int i = 0; i < 4; ++i)
#pragma unroll
    for (int j = 0; j < 4; ++j) acc[i][j] = fzero;

  const int r0 = tid >> 2, c0 = (tid & 3) << 3;
  const int r1 = (256 + tid) >> 2, c1 = ((256 + tid) & 3) << 3;
  const int wofs0 = (wid << 6) * 8;
  const int wofs1 = (256 + (wid << 6)) * 8;

  for (int kt = 0; kt < 16; ++kt) {
    const int k0 = kt << 6;
    async16(A + (size_t)(row0 + r0) * K + k0 + c0, sAh0 + wofs0);
    async16(A + (size_t)(row0 + r1) * K + k0 + c1, sAh0 + wofs1);
    async16(A + (size_t)(row0 + r0) * K + k0 + 32 + c0, sAh1 + wofs0);
    async16(A + (size_t)(row0 + r1) * K + k0 + 32 + c1, sAh1 + wofs1);
    async16(A2 + (size_t)(row0 + r0) * K + k0 + c0, sAl0 + wofs0);
    async16(A2 + (size_t)(row0 + r1) * K + k0 + c1, sAl0 + wofs1);
    async16(A2 + (size_t)(row0 + r0) * K + k0 + 32 + c0, sAl1 + wofs0);
    async16(A2 + (size_t)(row0 + r1) * K + k0 + 32 + c1, sAl1 + wofs1);
    async16(B + (size_t)(col0 + r0) * K + k0 + c0, sB0 + wofs0);
    async16(B + (size_t)(col0 + r1) * K + k0 + c1, sB0 + wofs1);
    async16(B + (size_t)(col0 + r0) * K + k0 + 32 + c0, sB1 + wofs0);
    async16(B + (size_t)(col0 + r1) * K + k0 + 32 + c1, sB1 + wofs1);
    __syncthreads();
    const int fr = lane & 15, fq = (lane >> 4) << 3;
#pragma unroll
    for (int t = 0; t < 2; ++t) {
      const bf16* sAh = t ? sAh1 : sAh0;
      const bf16* sAl = t ? sAl1 : sAl0;
      const bf16* sB = t ? sB1 : sB0;
      bf16x8 ah[4], al[4], bfr[4];
#pragma unroll
      for (int i = 0; i < 4; ++i) {
        ah[i] = *(const bf16x8*)&sAh[(wm * 64 + i * 16 + fr) * 32 + fq];
        al[i] = *(const bf16x8*)&sAl[(wm * 64 + i * 16 + fr) * 32 + fq];
      }
#pragma unroll
      for (int j = 0; j < 4; ++j)
        bfr[j] = *(const bf16x8*)&sB[(wn * 64 + j * 16 + fr) * 32 + fq];
#pragma unroll
      for (int i = 0; i < 4; ++i)
#pragma unroll
        for (int j = 0; j < 4; ++j) {
          acc[i][j] = __builtin_amdgcn_mfma_f32_16x16x32_bf16(
              ah[i], bfr[j], acc[i][j], 0, 0, 0);
          acc[i][j] = __builtin_amdgcn_mfma_f32_16x16x32_bf16(
              al[i], bfr[j], acc[i][j], 0, 0, 0);
        }
    }
    __syncthreads();
  }

  const int fr = lane & 15, fq4 = (lane >> 4) << 2;
#pragma unroll
  for (int i = 0; i < 4; ++i)
#pragma unroll
    for (int j = 0; j < 4; ++j) {
      const int rbase = row0 + wm * 64 + i * 16 + fq4;
      const int col = col0 + wn * 64 + j * 16 + fr;
#pragma unroll
      for (int r = 0; r < 4; ++r) {
        const size_t idx = (size_t)(rbase + r) * N + col;
        const float vs = acc[i][j][r] * scale;
        const bf16 hi = (bf16)vs;
        Chi[idx] = hi;
        Clo[idx] = (bf16)(vs - (float)hi);
      }
    }
}

// Q,K,V fused: grid (24, 32). bx>>3: 0=q (merged split, scale folds 1/8 AND
// log2e for the exp2 softmax), 1=k (merged split), 2=v (single-pass bf16 h,
// transposed store). ONE shared buffer (49152 B) for both paths.
__global__ __launch_bounds__(256) void gemm_qkv(
    const bf16* __restrict__ A, const bf16* __restrict__ A2,
    const bf16* __restrict__ Bq, const bf16* __restrict__ Bk,
    const bf16* __restrict__ Bv, bf16* qh, bf16* ql, bf16* kh, bf16* kl,
    bf16* vt) {
  __shared__ bf16 smem[24576];
  const int which = blockIdx.x >> 3;
  const int col0 = (blockIdx.x & 7) * 128, row0 = blockIdx.y * 128;
  if (which == 2) {
    gemm_body<5>(A, Bv, (void*)vt, nullptr, smem, col0, row0, 4096, 1024,
                 1024);
  } else {
    gemm_split_merged(A, A2, which ? Bk : Bq, which ? kh : qh, which ? kl : ql,
                      smem, which ? 1.0f : 0.125f * 1.44269504088896f, col0,
                      row0);
  }
}

// ---------------------------------------------------------------------------
// 128x64-tile GEMM, BK=128 as FOUR BK=32 sub-buffers per barrier pair.
// acc[4][2] = 32 AGPR -> more waves/SIMD; half the barrier drains per K;
// 2x blocks for residency. r1/r3 evidence: Wo, FF1, FF2 all improved here.
// EPI: 0 = f32, 2 = f32(acc+R), 3 = bf16 gelu(acc).
// ---------------------------------------------------------------------------
template <int EPI>
__global__ __launch_bounds__(256) void gemm_bt64(
    const bf16* __restrict__ A, const bf16* __restrict__ B,
    void* __restrict__ Cv, const float* __restrict__ R, int M, int N, int K) {
  __shared__ bf16 smem[24576];  // A: 4 x (128x32) = 16384; B: 4 x (64x32) = 8192
  const int col0 = blockIdx.x * 64, row0 = blockIdx.y * 128;
  const int tid = threadIdx.x;
  const int lane = tid & 63;
  const int wid = tid >> 6;
  const int wm = wid >> 1, wn = wid & 1;

  f32x4 acc[4][2];
  const f32x4 fzero = {0.f, 0.f, 0.f, 0.f};
#pragma unroll
  for (int i = 0; i < 4; ++i)
#pragma unroll
    for (int j = 0; j < 2; ++j) acc[i][j] = fzero;

  const int nk = K >> 7;
  const int r0 = tid >> 2, c0 = (tid & 3) << 3;
  const int r1 = (256 + tid) >> 2, c1 = ((256 + tid) & 3) << 3;
  const int wofs0 = (wid << 6) * 8;
  const int wofs1 = (256 + (wid << 6)) * 8;

  for (int kt = 0; kt < nk; ++kt) {
    const int k0 = kt << 7;
#pragma unroll
    for (int t = 0; t < 4; ++t) {
      bf16* sA = smem + t * 4096;
      bf16* sB = smem + 16384 + t * 2048;
      async16(A + (size_t)(row0 + r0) * K + k0 + t * 32 + c0, sA + wofs0);
      async16(A + (size_t)(row0 + r1) * K + k0 + t * 32 + c1, sA + wofs1);
      async16(B + (size_t)(col0 + r0) * K + k0 + t * 32 + c0, sB + wofs0);
    }
    __syncthreads();
    const int fr = lane & 15, fq = (lane >> 4) << 3;
#pragma unroll
    for (int t = 0; t < 4; ++t) {
      const bf16* sA = smem + t * 4096;
      const bf16* sB = smem + 16384 + t * 2048;
      bf16x8 af[4], bfr[2];
#pragma unroll
      for (int i = 0; i < 4; ++i)
        af[i] = *(const bf16x8*)&sA[(wm * 64 + i * 16 + fr) * 32 + fq];
#pragma unroll
      for (int j = 0; j < 2; ++j)
        bfr[j] = *(const bf16x8*)&sB[(wn * 32 + j * 16 + fr) * 32 + fq];
#pragma unroll
      for (int i = 0; i < 4; ++i)
#pragma unroll
        for (int j = 0; j < 2; ++j)
          acc[i][j] = __builtin_amdgcn_mfma_f32_16x16x32_bf16(
              af[i], bfr[j], acc[i][j], 0, 0, 0);
    }
    __syncthreads();
  }

  const int fr = lane & 15, fq4 = (lane >> 4) << 2;
#pragma unroll
  for (int i = 0; i < 4; ++i) {
#pragma unroll
    for (int j = 0; j < 2; ++j) {
      const int rbase = row0 + wm * 64 + i * 16 + fq4;
      const int col = col0 + wn * 32 + j * 16 + fr;
#pragma unroll
      for (int r = 0; r < 4; ++r) {
        const size_t idx = (size_t)(rbase + r) * N + col;
        const float val = acc[i][j][r];
        if constexpr (EPI == 3) {
          ((bf16*)Cv)[idx] =
              (bf16)(0.5f * val * (1.0f + erff(val * 0.7071067811865476f)));
        } else if constexpr (EPI == 2) {
          ((float*)Cv)[idx] = val + R[idx];
        } else {
          ((float*)Cv)[idx] = val;
        }
      }
    }
  }
}

// ---------------------------------------------------------------------------
// MFMA causal flash attention (64-query blocks) fused with cvt2
// (FF weights f32->bf16) in blocks [1024, 9216).
//  - logits in log2 domain (log2e folded into q scale) -> exp2f softmax
//  - Q fragments from global; next K/V tile register-prefetched
//  - 2 barriers/iter; P tile wave-private (stride 76, intra-wave RAW only)
//  - DPP rowmax softmax; LDS 37376 B -> 4 blocks/CU
//  - r1 POST-MORTEM: T5 setprio + T13 defer-rescale REGRESSED. DO NOT re-add.
//  - r2 mapping (RESTORED r5): qt = 31-(bid>>5), bh = (bid&7)*4+((bid>>3)&3).
//    CRITICAL locality property (r4 post-mortem): the 4 co-resident blocks
//    on a CU (bids u, u+256, u+512, u+768) share the SAME band bh — 4x L1
//    reuse of K/V. r4's "balanced" remap put 4 DIFFERENT bands per CU:
//    FETCH dropped but dur +8% (L2-latency exposure). DO NOT break
//    same-band-per-CU again.
//  - r4 (kept, r5 A/B): l = sum(P) via 2 extra MFMAs with B=ones — removes
//    rowsum16 DPP chains; VALUBusy 42 -> 36% (counter-confirmed r4).
//  - plain __launch_bounds__(256): (256,4) caused scratch spill — keep off
// ---------------------------------------------------------------------------
__global__ __launch_bounds__(256) void attn_cvt2(
    const bf16* __restrict__ qh_g, const bf16* __restrict__ ql_g,
    const bf16* __restrict__ kh_g, const bf16* __restrict__ kl_g,
    const bf16* __restrict__ vt_g, bf16* __restrict__ out,
    const float* __restrict__ Wf1, const float* __restrict__ Wf2,
    bf16* __restrict__ wdst) {
  __shared__ bf16 lds[18688];  // 37376 B
  const int tid = threadIdx.x;
  if (blockIdx.x >= 1024) {  // cvt2 path
    const size_t i = ((size_t)(blockIdx.x - 1024) * 256 + tid) * 4;
    const size_t M4 = 4u << 20;
    const float* src = (i < M4) ? Wf1 : Wf2;
    const size_t off = (i < M4) ? i : i - M4;
    const float4 v = *(const float4*)(src + off);
    bf16x4 o4 = {(bf16)v.x, (bf16)v.y, (bf16)v.z, (bf16)v.w};
    *(bf16x4*)(wdst + i) = o4;
    return;
  }
  bf16* Kh = lds;          // 64 x 72
  bf16* Kl = lds + 4608;   // 64 x 72
  bf16* Vt = lds + 9216;   // 64 x 72, rows = dim d, cols = key
  bf16* Ps = lds + 13824;  // 4 waves x 16 x 76 (wave-private)

  const int bid = blockIdx.x;
  // r2 mapping (restored): same band for all 4 co-resident blocks per CU.
  const int qt = 31 - (bid >> 5);  // long blocks first
  const int bh = (bid & 7) * 4 + ((bid >> 3) & 3);
  const int h = bh & 15;
  const int b = bh >> 4;
  const int t0 = qt << 6;
  const int w = tid >> 6;
  const int lane = tid & 63;
  const int c = lane & 15;
  const int quad = lane >> 4;

  const int r0 = tid >> 3, c0 = (tid & 7) << 3;
  const int r1 = (tid + 256) >> 3, c1 = ((tid + 256) & 7) << 3;

  // Q fragments straight from global (once per block)
  const size_t qrow =
      ((size_t)(b * 2048 + t0 + w * 16 + c)) * 1024 + h * 64 + quad * 8;
  bf16x8 aqh[2], aql[2];
  aqh[0] = *(const bf16x8*)&qh_g[qrow];
  aqh[1] = *(const bf16x8*)&qh_g[qrow + 32];
  aql[0] = *(const bf16x8*)&ql_g[qrow];
  aql[1] = *(const bf16x8*)&ql_g[qrow + 32];

  f32x4 o[4];
  const f32x4 fzero = {0.f, 0.f, 0.f, 0.f};
#pragma unroll
  for (int j = 0; j < 4; ++j) o[j] = fzero;
  f32x4 l4 = fzero;  // row-sum accumulator (MFMA with B=ones)
  float m_i[4] = {-3e38f, -3e38f, -3e38f, -3e38f};

  bf16x8 vone;
#pragma unroll
  for (int z = 0; z < 8; ++z) vone[z] = (bf16)1.0f;

  const size_t vtb = ((size_t)(b * 16 + h)) * 64 * 2048;  // + d*2048 + t
  const size_t kband = ((size_t)(b * 2048)) * 1024 + h * 64;

  bf16x8 gk[6];  // register prefetch of next K/V tile
  {
    gk[0] = *(const bf16x8*)&kh_g[kband + (size_t)r0 * 1024 + c0];
    gk[1] = *(const bf16x8*)&kh_g[kband + (size_t)r1 * 1024 + c1];
    gk[2] = *(const bf16x8*)&kl_g[kband + (size_t)r0 * 1024 + c0];
    gk[3] = *(const bf16x8*)&kl_g[kband + (size_t)r1 * 1024 + c1];
    gk[4] = *(const bf16x8*)&vt_g[vtb + (size_t)r0 * 2048 + c0];
    gk[5] = *(const bf16x8*)&vt_g[vtb + (size_t)r1 * 2048 + c1];
  }

  for (int kt = 0; kt <= qt; ++kt) {
    __syncthreads();  // (A) prev tile's fragment reads done before restage
    *(bf16x8*)&Kh[r0 * 72 + c0] = gk[0];
    *(bf16x8*)&Kh[r1 * 72 + c1] = gk[1];
    *(bf16x8*)&Kl[r0 * 72 + c0] = gk[2];
    *(bf16x8*)&Kl[r1 * 72 + c1] = gk[3];
    *(bf16x8*)&Vt[r0 * 72 + c0] = gk[4];
    *(bf16x8*)&Vt[r1 * 72 + c1] = gk[5];
    __syncthreads();  // (B) staging visible

    if (kt < qt) {  // prefetch next tile; latency hidden behind compute
      const int kb1 = (kt + 1) << 6;
      const size_t kbase = kband + (size_t)kb1 * 1024;
      gk[0] = *(const bf16x8*)&kh_g[kbase + (size_t)r0 * 1024 + c0];
      gk[1] = *(const bf16x8*)&kh_g[kbase + (size_t)r1 * 1024 + c1];
      gk[2] = *(const bf16x8*)&kl_g[kbase + (size_t)r0 * 1024 + c0];
      gk[3] = *(const bf16x8*)&kl_g[kbase + (size_t)r1 * 1024 + c1];
      gk[4] = *(const bf16x8*)&vt_g[vtb + (size_t)r0 * 2048 + kb1 + c0];
      gk[5] = *(const bf16x8*)&vt_g[vtb + (size_t)r1 * 2048 + kb1 + c1];
    }

    bf16x8 bkh[4][2], bkl[4][2];
#pragma unroll
    for (int j = 0; j < 4; ++j)
#pragma unroll
      for (int s2 = 0; s2 < 2; ++s2) {
        bkh[j][s2] = *(const bf16x8*)&Kh[(j * 16 + c) * 72 + s2 * 32 + quad * 8];
        bkl[j][s2] = *(const bf16x8*)&Kl[(j * 16 + c) * 72 + s2 * 32 + quad * 8];
      }

    f32x4 s4[4];
#pragma unroll
    for (int j = 0; j < 4; ++j) s4[j] = fzero;
#pragma unroll
    for (int j = 0; j < 4; ++j)
#pragma unroll
      for (int s2 = 0; s2 < 2; ++s2) {
        s4[j] = __builtin_amdgcn_mfma_f32_16x16x32_bf16(aqh[s2], bkh[j][s2], s4[j], 0, 0, 0);
        s4[j] = __builtin_amdgcn_mfma_f32_16x16x32_bf16(aqh[s2], bkl[j][s2], s4[j], 0, 0, 0);
        s4[j] = __builtin_amdgcn_mfma_f32_16x16x32_bf16(aql[s2], bkh[j][s2], s4[j], 0, 0, 0);
      }

    if (kt == qt) {  // diagonal tile: strict-upper mask (t0 == kb)
#pragma unroll
      for (int j = 0; j < 4; ++j)
#pragma unroll
        for (int r = 0; r < 4; ++r)
          if (j * 16 + c > w * 16 + quad * 4 + r) s4[j][r] = -3e38f;
    }

    float p[4][4];
#pragma unroll
    for (int r = 0; r < 4; ++r) {
      float mt = fmaxf(fmaxf(s4[0][r], s4[1][r]), fmaxf(s4[2][r], s4[3][r]));
      mt = rowmax16(mt);  // DPP row reduce
      const float mn = fmaxf(m_i[r], mt);
      const float al = exp2f(m_i[r] - mn);  // logits already in log2 domain
      m_i[r] = mn;
#pragma unroll
      for (int j = 0; j < 4; ++j) p[r][j] = exp2f(s4[j][r] - mn);
      l4[r] *= al;
#pragma unroll
      for (int j = 0; j < 4; ++j) o[j][r] *= al;
    }

    // P -> wave-private region, stride 76 (conflict-free; intra-wave RAW only)
    bf16* Pw = Ps + w * 16 * 76;
#pragma unroll
    for (int r = 0; r < 4; ++r)
#pragma unroll
      for (int j = 0; j < 4; ++j)
        Pw[(quad * 4 + r) * 76 + j * 16 + c] = (bf16)p[r][j];

    bf16x8 ap[2], bv[4][2];
#pragma unroll
    for (int s2 = 0; s2 < 2; ++s2)
      ap[s2] = *(const bf16x8*)&Pw[c * 76 + s2 * 32 + quad * 8];
#pragma unroll
    for (int j = 0; j < 4; ++j)
#pragma unroll
      for (int s2 = 0; s2 < 2; ++s2)
        bv[j][s2] = *(const bf16x8*)&Vt[(j * 16 + c) * 72 + s2 * 32 + quad * 8];
    // l row-sum via MFMA (B = ones): D[m][n] = sum_k P[m][k], all n equal.
    l4 = __builtin_amdgcn_mfma_f32_16x16x32_bf16(ap[0], vone, l4, 0, 0, 0);
    l4 = __builtin_amdgcn_mfma_f32_16x16x32_bf16(ap[1], vone, l4, 0, 0, 0);
#pragma unroll
    for (int j = 0; j < 4; ++j)
#pragma unroll
      for (int s2 = 0; s2 < 2; ++s2)
        o[j] = __builtin_amdgcn_mfma_f32_16x16x32_bf16(ap[s2], bv[j][s2], o[j], 0, 0, 0);
  }

#pragma unroll
  for (int r = 0; r < 4; ++r) {
    const float inv = 1.0f / l4[r];
#pragma unroll
    for (int j = 0; j < 4; ++j) {
      const size_t oi =
          ((size_t)(b * 2048 + t0 + w * 16 + quad * 4 + r)) * 1024 + h * 64 +
          j * 16 + c;
      out[oi] = (bf16)(o[j][r] * inv);
    }
  }
}

// ---------------------------------------------------------------------------
// Workspace plan (80 MiB peak; >104 MiB previously corrupted harness memory):
//   [ 0, 8)   Wq|Wk|Wv|Wo bf16
//   [ 8,24)   h_hi|h_lo  -> (after gemm_qkv) Wf1_b|Wf2_b   (attn_cvt2 fills)
//   [24,40)   qh|ql      -> (after attn)   x1 (f32)
//   [40,72)   kh|kl|vt|attnout -> (after Wo) ff (bf16 4096x4096)
//   [72,80)   h2
// ---------------------------------------------------------------------------
extern "C" void kernel_launch(void* const* d_in, const int* in_sizes, int n_in,
                              void* d_out, int out_size, void* d_ws,
                              size_t ws_size, hipStream_t stream) {
  const float* x = (const float*)d_in[0];
  const float* g1 = (const float*)d_in[2];
  const float* b1 = (const float*)d_in[3];
  const float* g2 = (const float*)d_in[4];
  const float* b2 = (const float*)d_in[5];
  const float* Wq = (const float*)d_in[6];
  const float* Wk = (const float*)d_in[7];
  const float* Wv = (const float*)d_in[8];
  const float* Wo = (const float*)d_in[9];
  const float* Wf1 = (const float*)d_in[10];
  const float* Wf2 = (const float*)d_in[11];
  char* ws = (char*)d_ws;
  const size_t MB = 1024 * 1024;
  const size_t M1 = 1u << 20;
  bf16* Wq_b = (bf16*)ws;
  bf16* Wk_b = Wq_b + 1 * M1;
  bf16* Wv_b = Wq_b + 2 * M1;
  bf16* Wo_b = Wq_b + 3 * M1;
  bf16* h_hi = (bf16*)(ws + 8 * MB);
  bf16* h_lo = (bf16*)(ws + 16 * MB);
  bf16* Wf1_b = h_hi;  // alias: h dead after gemm_qkv; attn_cvt2 fills
  bf16* Wf2_b = h_lo;
  bf16* qh = (bf16*)(ws + 24 * MB);
  bf16* ql = (bf16*)(ws + 32 * MB);
  bf16* kh = (bf16*)(ws + 40 * MB);
  bf16* kl = (bf16*)(ws + 48 * MB);
  bf16* vt = (bf16*)(ws + 56 * MB);
  bf16* attnout = (bf16*)(ws + 64 * MB);
  float* x1 = (float*)qh;  // alias: qh/ql dead after attn
  bf16* h2 = (bf16*)(ws + 72 * MB);
  bf16* ff = kh;  // alias: kh/kl/vt/attnout dead after Wo GEMM
  float* outp = (float*)d_out;

  // 1) LN1 (split bf16 hi/lo) + cvt4 (attention weights) in one launch
  ln1_cvt4<<<8192, 256, 0, stream>>>(x, g1, b1, h_hi, h_lo, Wq, Wk, Wv, Wo,
                                     Wq_b);
  // 2) Q,K (merged split bf16, q scale = 1/8*log2e) + V^T fused
  gemm_qkv<<<dim3(24, 32), 256, 0, stream>>>(h_hi, h_lo, Wq_b, Wk_b, Wv_b, qh,
                                             ql, kh, kl, vt);
  // 3) attention (blocks 0..1023) + cvt2 FF weights (blocks 1024..9215)
  attn_cvt2<<<9216, 256, 0, stream>>>(qh, ql, kh, kl, vt, attnout, Wf1, Wf2,
                                      Wf1_b);
  // 4) x1 = x + attnout @ Wo^T   (f32; overwrites dead qh/ql) — 64N tiles
  gemm_bt64<2><<<dim3(16, 32), 256, 0, stream>>>(attnout, Wo_b, (void*)x1, x,
                                                 4096, 1024, 1024);
  // 5) LN2 -> h2 (bf16)
  ln_kernel<<<4096, 256, 0, stream>>>(x1, g2, b2, h2);
  // 6) ff = gelu(h2 @ Wff1^T)  (bf16; 128x64 tiles, BK=128)
  gemm_bt64<3><<<dim3(64, 32), 256, 0, stream>>>(h2, Wf1_b, (void*)ff, nullptr,
                                                 4096, 4096, 1024);
  // 7) out = x1 + ff @ Wff2^T  (f32) — 64N tiles
  gemm_bt64<2><<<dim3(16, 32), 256, 0, stream>>>(ff, Wf2_b, (void*)outp, x1,
                                                 4096, 1024, 4096);
}

// Round 7
// 408.067 us; speedup vs baseline: 1.0209x; 1.0013x over previous
//
#include <hip/hip_runtime.h>

typedef __bf16 bf16;
typedef bf16 bf16x8 __attribute__((ext_vector_type(8)));
typedef bf16 bf16x4 __attribute__((ext_vector_type(4)));
typedef float f32x4 __attribute__((ext_vector_type(4)));

// ---------------------------------------------------------------------------
// async global->LDS 16B copy (wave-uniform LDS base + lane*16 placement)
// ---------------------------------------------------------------------------
static __device__ __forceinline__ void async16(const void* g, void* l) {
  __builtin_amdgcn_global_load_lds((__attribute__((address_space(1))) void*)g,
                                   (__attribute__((address_space(3))) void*)l,
                                   16, 0, 0);
}

// DPP row_ror:N within 16-lane rows (VALU-only cross-lane; no LDS pipe).
template <int N>
static __device__ __forceinline__ float ror16(float x) {
  const int y =
      __builtin_amdgcn_update_dpp(0, __float_as_int(x), 0x120 | N, 0xf, 0xf, true);
  return __int_as_float(y);
}
static __device__ __forceinline__ float rowmax16(float x) {
  x = fmaxf(x, ror16<8>(x));
  x = fmaxf(x, ror16<4>(x));
  x = fmaxf(x, ror16<2>(x));
  x = fmaxf(x, ror16<1>(x));
  return x;
}

// ---------------------------------------------------------------------------
// LN1 (split bf16 hi/lo) fused with cvt4 (attention weights f32->bf16).
// blocks [0,4096): LN rows; blocks [4096,8192): weight conversion chunks.
// ---------------------------------------------------------------------------
__global__ __launch_bounds__(256) void ln1_cvt4(
    const float* __restrict__ x, const float* __restrict__ g,
    const float* __restrict__ b, bf16* __restrict__ hi, bf16* __restrict__ lo,
    const float* __restrict__ Wq, const float* __restrict__ Wk,
    const float* __restrict__ Wv, const float* __restrict__ Wo,
    bf16* __restrict__ wdst) {
  const int tid = threadIdx.x;
  if (blockIdx.x >= 4096) {  // cvt4 path
    const size_t i = ((size_t)(blockIdx.x - 4096) * 256 + tid) * 4;
    const size_t M1 = 1u << 20;
    const float* src = (i < M1) ? Wq : (i < 2 * M1) ? Wk : (i < 3 * M1) ? Wv : Wo;
    const size_t off = i & (M1 - 1);
    const float4 v = *(const float4*)(src + off);
    bf16x4 o = {(bf16)v.x, (bf16)v.y, (bf16)v.z, (bf16)v.w};
    *(bf16x4*)(wdst + i) = o;
    return;
  }
  const int row = blockIdx.x;
  const float* xr = x + (size_t)row * 1024;
  float v[4];
  float s1 = 0.f, s2 = 0.f;
#pragma unroll
  for (int j = 0; j < 4; ++j) {
    v[j] = xr[j * 256 + tid];
    s1 += v[j];
    s2 += v[j] * v[j];
  }
#pragma unroll
  for (int off = 1; off < 64; off <<= 1) {
    s1 += __shfl_xor(s1, off);
    s2 += __shfl_xor(s2, off);
  }
  __shared__ float ws1[4], ws2[4];
  const int wid = tid >> 6;
  if ((tid & 63) == 0) {
    ws1[wid] = s1;
    ws2[wid] = s2;
  }
  __syncthreads();
  s1 = ws1[0] + ws1[1] + ws1[2] + ws1[3];
  s2 = ws2[0] + ws2[1] + ws2[2] + ws2[3];
  const float mu = s1 * (1.f / 1024.f);
  const float var = s2 * (1.f / 1024.f) - mu * mu;
  const float rstd = 1.0f / sqrtf(var + 1e-5f);
#pragma unroll
  for (int j = 0; j < 4; ++j) {
    const int cc = j * 256 + tid;
    const float y = (v[j] - mu) * rstd * g[cc] + b[cc];
    const bf16 yh = (bf16)y;
    hi[(size_t)row * 1024 + cc] = yh;
    lo[(size_t)row * 1024 + cc] = (bf16)(y - (float)yh);
  }
}

// ---------------------------------------------------------------------------
// LayerNorm over D=1024 (f32 input), one block per row (non-split).
// ---------------------------------------------------------------------------
__global__ __launch_bounds__(256) void ln_kernel(
    const float* __restrict__ x, const float* __restrict__ g,
    const float* __restrict__ b, bf16* __restrict__ hi) {
  const int row = blockIdx.x;
  const int tid = threadIdx.x;
  const float* xr = x + (size_t)row * 1024;
  float v[4];
  float s1 = 0.f, s2 = 0.f;
#pragma unroll
  for (int j = 0; j < 4; ++j) {
    v[j] = xr[j * 256 + tid];
    s1 += v[j];
    s2 += v[j] * v[j];
  }
#pragma unroll
  for (int off = 1; off < 64; off <<= 1) {
    s1 += __shfl_xor(s1, off);
    s2 += __shfl_xor(s2, off);
  }
  __shared__ float ws1[4], ws2[4];
  const int wid = tid >> 6;
  if ((tid & 63) == 0) {
    ws1[wid] = s1;
    ws2[wid] = s2;
  }
  __syncthreads();
  s1 = ws1[0] + ws1[1] + ws1[2] + ws1[3];
  s2 = ws2[0] + ws2[1] + ws2[2] + ws2[3];
  const float mu = s1 * (1.f / 1024.f);
  const float var = s2 * (1.f / 1024.f) - mu * mu;
  const float rstd = 1.0f / sqrtf(var + 1e-5f);
#pragma unroll
  for (int j = 0; j < 4; ++j) {
    const int cc = j * 256 + tid;
    const float y = (v[j] - mu) * rstd * g[cc] + b[cc];
    hi[(size_t)row * 1024 + cc] = (bf16)y;
  }
}

// ---------------------------------------------------------------------------
// GEMM body: C[M,N] = A[M,K] * B[N,K]^T   (m97 structure, BK=64 as two BK=32
// sub-buffers per barrier pair). Used by gemm_qkv (EPI=5 V^T path).
// ---------------------------------------------------------------------------
template <int EPI>
static __device__ __forceinline__ void gemm_body(
    const bf16* __restrict__ A, const bf16* __restrict__ B,
    void* __restrict__ Cv, const float* __restrict__ R, bf16* smem, int col0,
    int row0, int M, int N, int K) {
  bf16* sA0 = smem;          // 128 x 32
  bf16* sA1 = smem + 4096;   // 128 x 32 (k+32)
  bf16* sB0 = smem + 8192;   // 128 x 32
  bf16* sB1 = smem + 12288;  // 128 x 32 (k+32)
  const int tid = threadIdx.x;
  const int lane = tid & 63;
  const int wid = tid >> 6;
  const int wm = wid >> 1, wn = wid & 1;

  f32x4 acc[4][4];
  const f32x4 fzero = {0.f, 0.f, 0.f, 0.f};
#pragma unroll
  for (int i = 0; i < 4; ++i)
#pragma unroll
    for (int j = 0; j < 4; ++j) acc[i][j] = fzero;

  const int nk = K >> 6;
  const int r0 = tid >> 2, c0 = (tid & 3) << 3;
  const int r1 = (256 + tid) >> 2, c1 = ((256 + tid) & 3) << 3;
  const int wofs0 = (wid << 6) * 8;  // wave-uniform LDS offsets
  const int wofs1 = (256 + (wid << 6)) * 8;

  for (int kt = 0; kt < nk; ++kt) {
    const int k0 = kt << 6;
    async16(A + (size_t)(row0 + r0) * K + k0 + c0, sA0 + wofs0);
    async16(A + (size_t)(row0 + r1) * K + k0 + c1, sA0 + wofs1);
    async16(A + (size_t)(row0 + r0) * K + k0 + 32 + c0, sA1 + wofs0);
    async16(A + (size_t)(row0 + r1) * K + k0 + 32 + c1, sA1 + wofs1);
    async16(B + (size_t)(col0 + r0) * K + k0 + c0, sB0 + wofs0);
    async16(B + (size_t)(col0 + r1) * K + k0 + c1, sB0 + wofs1);
    async16(B + (size_t)(col0 + r0) * K + k0 + 32 + c0, sB1 + wofs0);
    async16(B + (size_t)(col0 + r1) * K + k0 + 32 + c1, sB1 + wofs1);
    __syncthreads();
    const int fr = lane & 15, fq = (lane >> 4) << 3;
#pragma unroll
    for (int t = 0; t < 2; ++t) {
      const bf16* sA = t ? sA1 : sA0;
      const bf16* sB = t ? sB1 : sB0;
      bf16x8 af[4], bfr[4];
#pragma unroll
      for (int i = 0; i < 4; ++i)
        af[i] = *(const bf16x8*)&sA[(wm * 64 + i * 16 + fr) * 32 + fq];
#pragma unroll
      for (int j = 0; j < 4; ++j)
        bfr[j] = *(const bf16x8*)&sB[(wn * 64 + j * 16 + fr) * 32 + fq];
#pragma unroll
      for (int i = 0; i < 4; ++i)
#pragma unroll
        for (int j = 0; j < 4; ++j)
          acc[i][j] = __builtin_amdgcn_mfma_f32_16x16x32_bf16(
              af[i], bfr[j], acc[i][j], 0, 0, 0);
    }
    __syncthreads();
  }

  // C/D layout (m89-verified): col = lane&15, row = (lane>>4)*4 + reg
  const int fr = lane & 15, fq4 = (lane >> 4) << 2;
#pragma unroll
  for (int i = 0; i < 4; ++i) {
#pragma unroll
    for (int j = 0; j < 4; ++j) {
      const int rbase = row0 + wm * 64 + i * 16 + fq4;
      const int col = col0 + wn * 64 + j * 16 + fr;
      if constexpr (EPI == 5) {
        const int b = rbase >> 11, t = rbase & 2047;
        const int hh = col >> 6, d = col & 63;
        bf16x4 o4 = {(bf16)acc[i][j][0], (bf16)acc[i][j][1],
                     (bf16)acc[i][j][2], (bf16)acc[i][j][3]};
        *(bf16x4*)&((bf16*)Cv)[(((size_t)(b * 16 + hh)) * 64 + d) * 2048 + t] =
            o4;
      } else {
#pragma unroll
        for (int r = 0; r < 4; ++r) {
          const size_t idx = (size_t)(rbase + r) * N + col;
          const float val = acc[i][j][r];
          if constexpr (EPI == 0) {
            ((float*)Cv)[idx] = val;
          } else if constexpr (EPI == 2) {
            ((float*)Cv)[idx] = val + R[idx];
          } else {  // EPI == 3
            ((bf16*)Cv)[idx] =
                (bf16)(0.5f * val * (1.0f + erff(val * 0.7071067811865476f)));
          }
        }
      }
    }
  }
}

// ---------------------------------------------------------------------------
// Merged split-K GEMM for q/k (BK=64, two sub-steps per barrier): stages
// A_hi, A_lo AND B each k-step (B loaded ONCE). Split bf16 hi/lo epilogue.
// ---------------------------------------------------------------------------
static __device__ __forceinline__ void gemm_split_merged(
    const bf16* __restrict__ A, const bf16* __restrict__ A2,
    const bf16* __restrict__ B, bf16* __restrict__ Chi, bf16* __restrict__ Clo,
    bf16* smem, float scale, int col0, int row0) {
  constexpr int K = 1024, N = 1024;
  bf16* sAh0 = smem;           // 128 x 32
  bf16* sAh1 = smem + 4096;    // k+32
  bf16* sAl0 = smem + 8192;
  bf16* sAl1 = smem + 12288;
  bf16* sB0 = smem + 16384;
  bf16* sB1 = smem + 20480;
  const int tid = threadIdx.x;
  const int lane = tid & 63;
  const int wid = tid >> 6;
  const int wm = wid >> 1, wn = wid & 1;

  f32x4 acc[4][4];
  const f32x4 fzero = {0.f, 0.f, 0.f, 0.f};
#pragma unroll
  for (int i = 0; i < 4; ++i)
#pragma unroll
    for (int j = 0; j < 4; ++j) acc[i][j] = fzero;

  const int r0 = tid >> 2, c0 = (tid & 3) << 3;
  const int r1 = (256 + tid) >> 2, c1 = ((256 + tid) & 3) << 3;
  const int wofs0 = (wid << 6) * 8;
  const int wofs1 = (256 + (wid << 6)) * 8;

  for (int kt = 0; kt < 16; ++kt) {
    const int k0 = kt << 6;
    async16(A + (size_t)(row0 + r0) * K + k0 + c0, sAh0 + wofs0);
    async16(A + (size_t)(row0 + r1) * K + k0 + c1, sAh0 + wofs1);
    async16(A + (size_t)(row0 + r0) * K + k0 + 32 + c0, sAh1 + wofs0);
    async16(A + (size_t)(row0 + r1) * K + k0 + 32 + c1, sAh1 + wofs1);
    async16(A2 + (size_t)(row0 + r0) * K + k0 + c0, sAl0 + wofs0);
    async16(A2 + (size_t)(row0 + r1) * K + k0 + c1, sAl0 + wofs1);
    async16(A2 + (size_t)(row0 + r0) * K + k0 + 32 + c0, sAl1 + wofs0);
    async16(A2 + (size_t)(row0 + r1) * K + k0 + 32 + c1, sAl1 + wofs1);
    async16(B + (size_t)(col0 + r0) * K + k0 + c0, sB0 + wofs0);
    async16(B + (size_t)(col0 + r1) * K + k0 + c1, sB0 + wofs1);
    async16(B + (size_t)(col0 + r0) * K + k0 + 32 + c0, sB1 + wofs0);
    async16(B + (size_t)(col0 + r1) * K + k0 + 32 + c1, sB1 + wofs1);
    __syncthreads();
    const int fr = lane & 15, fq = (lane >> 4) << 3;
#pragma unroll
    for (int t = 0; t < 2; ++t) {
      const bf16* sAh = t ? sAh1 : sAh0;
      const bf16* sAl = t ? sAl1 : sAl0;
      const bf16* sB = t ? sB1 : sB0;
      bf16x8 ah[4], al[4], bfr[4];
#pragma unroll
      for (int i = 0; i < 4; ++i) {
        ah[i] = *(const bf16x8*)&sAh[(wm * 64 + i * 16 + fr) * 32 + fq];
        al[i] = *(const bf16x8*)&sAl[(wm * 64 + i * 16 + fr) * 32 + fq];
      }
#pragma unroll
      for (int j = 0; j < 4; ++j)
        bfr[j] = *(const bf16x8*)&sB[(wn * 64 + j * 16 + fr) * 32 + fq];
#pragma unroll
      for (int i = 0; i < 4; ++i)
#pragma unroll
        for (int j = 0; j < 4; ++j) {
          acc[i][j] = __builtin_amdgcn_mfma_f32_16x16x32_bf16(
              ah[i], bfr[j], acc[i][j], 0, 0, 0);
          acc[i][j] = __builtin_amdgcn_mfma_f32_16x16x32_bf16(
              al[i], bfr[j], acc[i][j], 0, 0, 0);
        }
    }
    __syncthreads();
  }

  const int fr = lane & 15, fq4 = (lane >> 4) << 2;
#pragma unroll
  for (int i = 0; i < 4; ++i)
#pragma unroll
    for (int j = 0; j < 4; ++j) {
      const int rbase = row0 + wm * 64 + i * 16 + fq4;
      const int col = col0 + wn * 64 + j * 16 + fr;
#pragma unroll
      for (int r = 0; r < 4; ++r) {
        const size_t idx = (size_t)(rbase + r) * N + col;
        const float vs = acc[i][j][r] * scale;
        const bf16 hi = (bf16)vs;
        Chi[idx] = hi;
        Clo[idx] = (bf16)(vs - (float)hi);
      }
    }
}

// Q,K,V fused: grid (24, 32). bx>>3: 0=q (merged split, scale folds 1/8 AND
// log2e for the exp2 softmax), 1=k (merged split), 2=v (single-pass bf16 h,
// transposed store). ONE shared buffer (49152 B) for both paths.
__global__ __launch_bounds__(256) void gemm_qkv(
    const bf16* __restrict__ A, const bf16* __restrict__ A2,
    const bf16* __restrict__ Bq, const bf16* __restrict__ Bk,
    const bf16* __restrict__ Bv, bf16* qh, bf16* ql, bf16* kh, bf16* kl,
    bf16* vt) {
  __shared__ bf16 smem[24576];
  const int which = blockIdx.x >> 3;
  const int col0 = (blockIdx.x & 7) * 128, row0 = blockIdx.y * 128;
  if (which == 2) {
    gemm_body<5>(A, Bv, (void*)vt, nullptr, smem, col0, row0, 4096, 1024,
                 1024);
  } else {
    gemm_split_merged(A, A2, which ? Bk : Bq, which ? kh : qh, which ? kl : ql,
                      smem, which ? 1.0f : 0.125f * 1.44269504088896f, col0,
                      row0);
  }
}

// ---------------------------------------------------------------------------
// 128x64-tile GEMM, BK=128 as FOUR BK=32 sub-buffers per barrier pair.
// acc[4][2] = 32 AGPR -> more waves/SIMD; half the barrier drains per K;
// 2x blocks for residency. r1/r3 evidence: Wo, FF1, FF2 all improved here.
// EPI: 0 = f32, 2 = f32(acc+R), 3 = bf16 gelu(acc).
// ---------------------------------------------------------------------------
template <int EPI>
__global__ __launch_bounds__(256) void gemm_bt64(
    const bf16* __restrict__ A, const bf16* __restrict__ B,
    void* __restrict__ Cv, const float* __restrict__ R, int M, int N, int K) {
  __shared__ bf16 smem[24576];  // A: 4 x (128x32) = 16384; B: 4 x (64x32) = 8192
  const int col0 = blockIdx.x * 64, row0 = blockIdx.y * 128;
  const int tid = threadIdx.x;
  const int lane = tid & 63;
  const int wid = tid >> 6;
  const int wm = wid >> 1, wn = wid & 1;

  f32x4 acc[4][2];
  const f32x4 fzero = {0.f, 0.f, 0.f, 0.f};
#pragma unroll
  for (int i = 0; i < 4; ++i)
#pragma unroll
    for (int j = 0; j < 2; ++j) acc[i][j] = fzero;

  const int nk = K >> 7;
  const int r0 = tid >> 2, c0 = (tid & 3) << 3;
  const int r1 = (256 + tid) >> 2, c1 = ((256 + tid) & 3) << 3;
  const int wofs0 = (wid << 6) * 8;
  const int wofs1 = (256 + (wid << 6)) * 8;

  for (int kt = 0; kt < nk; ++kt) {
    const int k0 = kt << 7;
#pragma unroll
    for (int t = 0; t < 4; ++t) {
      bf16* sA = smem + t * 4096;
      bf16* sB = smem + 16384 + t * 2048;
      async16(A + (size_t)(row0 + r0) * K + k0 + t * 32 + c0, sA + wofs0);
      async16(A + (size_t)(row0 + r1) * K + k0 + t * 32 + c1, sA + wofs1);
      async16(B + (size_t)(col0 + r0) * K + k0 + t * 32 + c0, sB + wofs0);
    }
    __syncthreads();
    const int fr = lane & 15, fq = (lane >> 4) << 3;
#pragma unroll
    for (int t = 0; t < 4; ++t) {
      const bf16* sA = smem + t * 4096;
      const bf16* sB = smem + 16384 + t * 2048;
      bf16x8 af[4], bfr[2];
#pragma unroll
      for (int i = 0; i < 4; ++i)
        af[i] = *(const bf16x8*)&sA[(wm * 64 + i * 16 + fr) * 32 + fq];
#pragma unroll
      for (int j = 0; j < 2; ++j)
        bfr[j] = *(const bf16x8*)&sB[(wn * 32 + j * 16 + fr) * 32 + fq];
#pragma unroll
      for (int i = 0; i < 4; ++i)
#pragma unroll
        for (int j = 0; j < 2; ++j)
          acc[i][j] = __builtin_amdgcn_mfma_f32_16x16x32_bf16(
              af[i], bfr[j], acc[i][j], 0, 0, 0);
    }
    __syncthreads();
  }

  const int fr = lane & 15, fq4 = (lane >> 4) << 2;
#pragma unroll
  for (int i = 0; i < 4; ++i) {
#pragma unroll
    for (int j = 0; j < 2; ++j) {
      const int rbase = row0 + wm * 64 + i * 16 + fq4;
      const int col = col0 + wn * 32 + j * 16 + fr;
#pragma unroll
      for (int r = 0; r < 4; ++r) {
        const size_t idx = (size_t)(rbase + r) * N + col;
        const float val = acc[i][j][r];
        if constexpr (EPI == 3) {
          ((bf16*)Cv)[idx] =
              (bf16)(0.5f * val * (1.0f + erff(val * 0.7071067811865476f)));
        } else if constexpr (EPI == 2) {
          ((float*)Cv)[idx] = val + R[idx];
        } else {
          ((float*)Cv)[idx] = val;
        }
      }
    }
  }
}

// ---------------------------------------------------------------------------
// MFMA causal flash attention (64-query blocks) fused with cvt2
// (FF weights f32->bf16) in blocks [1024, 9216).
//  - logits in log2 domain (log2e folded into q scale) -> exp2f softmax
//  - Q fragments from global; next K/V tile register-prefetched
//  - 2 barriers/iter; P tile wave-private (stride 76, intra-wave RAW only)
//  - DPP rowmax softmax; LDS 37376 B -> 4 blocks/CU
//  - r1 POST-MORTEM: T5 setprio + T13 defer-rescale REGRESSED. DO NOT re-add.
//  - r4/r6: l = sum(P) via 2 extra MFMAs with B=ones — CONFIRMED WIN
//    (r6 A/B vs r3: 106.7 -> 103.3 us, VALUBusy 41.8 -> 39.7).
//  - LOCALITY INVARIANT (r4 post-mortem): co-resident blocks (bids u,
//    u+256, u+512, u+768) MUST share the same band bh -> bh must depend
//    only on u = bid&255. r4 broke this: FETCH dropped but dur +8%.
//  - r7 NEW: balanced qt WITHIN the bh-invariant family. bh(u) unchanged;
//    qt now depends on (v = u>>5, s = bid>>8) via base = (3-s)*8,
//    qt = base + (s odd ? v : 7-v). Co-resident qts sum to 62 for every
//    v -> per-CU tile-iters = 66 uniformly (was 80-4v in [52,80]).
//    Bijective: s covers ranges {24-31},{16-23},{8-15},{0-7}. s=0 still
//    dispatches the longest blocks first.
//  - plain __launch_bounds__(256): (256,4) caused scratch spill — keep off
// ---------------------------------------------------------------------------
__global__ __launch_bounds__(256) void attn_cvt2(
    const bf16* __restrict__ qh_g, const bf16* __restrict__ ql_g,
    const bf16* __restrict__ kh_g, const bf16* __restrict__ kl_g,
    const bf16* __restrict__ vt_g, bf16* __restrict__ out,
    const float* __restrict__ Wf1, const float* __restrict__ Wf2,
    bf16* __restrict__ wdst) {
  __shared__ bf16 lds[18688];  // 37376 B
  const int tid = threadIdx.x;
  if (blockIdx.x >= 1024) {  // cvt2 path
    const size_t i = ((size_t)(blockIdx.x - 1024) * 256 + tid) * 4;
    const size_t M4 = 4u << 20;
    const float* src = (i < M4) ? Wf1 : Wf2;
    const size_t off = (i < M4) ? i : i - M4;
    const float4 v = *(const float4*)(src + off);
    bf16x4 o4 = {(bf16)v.x, (bf16)v.y, (bf16)v.z, (bf16)v.w};
    *(bf16x4*)(wdst + i) = o4;
    return;
  }
  bf16* Kh = lds;          // 64 x 72
  bf16* Kl = lds + 4608;   // 64 x 72
  bf16* Vt = lds + 9216;   // 64 x 72, rows = dim d, cols = key
  bf16* Ps = lds + 13824;  // 4 waves x 16 x 76 (wave-private)

  const int bid = blockIdx.x;
  // r7 mapping: bh depends only on u (locality invariant); qt balanced
  // across resident sets s so every CU totals 66 tile-iters.
  const int u = bid & 255;
  const int s = bid >> 8;        // resident-set index 0..3
  const int v = u >> 5;          // 0..7
  const int qbase = (3 - s) << 3;
  const int qt = qbase + ((s & 1) ? v : 7 - v);
  const int bh = (u & 7) * 4 + ((u >> 3) & 3);
  const int h = bh & 15;
  const int b = bh >> 4;
  const int t0 = qt << 6;
  const int w = tid >> 6;
  const int lane = tid & 63;
  const int c = lane & 15;
  const int quad = lane >> 4;

  const int r0 = tid >> 3, c0 = (tid & 7) << 3;
  const int r1 = (tid + 256) >> 3, c1 = ((tid + 256) & 7) << 3;

  // Q fragments straight from global (once per block)
  const size_t qrow =
      ((size_t)(b * 2048 + t0 + w * 16 + c)) * 1024 + h * 64 + quad * 8;
  bf16x8 aqh[2], aql[2];
  aqh[0] = *(const bf16x8*)&qh_g[qrow];
  aqh[1] = *(const bf16x8*)&qh_g[qrow + 32];
  aql[0] = *(const bf16x8*)&ql_g[qrow];
  aql[1] = *(const bf16x8*)&ql_g[qrow + 32];

  f32x4 o[4];
  const f32x4 fzero = {0.f, 0.f, 0.f, 0.f};
#pragma unroll
  for (int j = 0; j < 4; ++j) o[j] = fzero;
  f32x4 l4 = fzero;  // row-sum accumulator (MFMA with B=ones)
  float m_i[4] = {-3e38f, -3e38f, -3e38f, -3e38f};

  bf16x8 vone;
#pragma unroll
  for (int z = 0; z < 8; ++z) vone[z] = (bf16)1.0f;

  const size_t vtb = ((size_t)(b * 16 + h)) * 64 * 2048;  // + d*2048 + t
  const size_t kband = ((size_t)(b * 2048)) * 1024 + h * 64;

  bf16x8 gk[6];  // register prefetch of next K/V tile
  {
    gk[0] = *(const bf16x8*)&kh_g[kband + (size_t)r0 * 1024 + c0];
    gk[1] = *(const bf16x8*)&kh_g[kband + (size_t)r1 * 1024 + c1];
    gk[2] = *(const bf16x8*)&kl_g[kband + (size_t)r0 * 1024 + c0];
    gk[3] = *(const bf16x8*)&kl_g[kband + (size_t)r1 * 1024 + c1];
    gk[4] = *(const bf16x8*)&vt_g[vtb + (size_t)r0 * 2048 + c0];
    gk[5] = *(const bf16x8*)&vt_g[vtb + (size_t)r1 * 2048 + c1];
  }

  for (int kt = 0; kt <= qt; ++kt) {
    __syncthreads();  // (A) prev tile's fragment reads done before restage
    *(bf16x8*)&Kh[r0 * 72 + c0] = gk[0];
    *(bf16x8*)&Kh[r1 * 72 + c1] = gk[1];
    *(bf16x8*)&Kl[r0 * 72 + c0] = gk[2];
    *(bf16x8*)&Kl[r1 * 72 + c1] = gk[3];
    *(bf16x8*)&Vt[r0 * 72 + c0] = gk[4];
    *(bf16x8*)&Vt[r1 * 72 + c1] = gk[5];
    __syncthreads();  // (B) staging visible

    if (kt < qt) {  // prefetch next tile; latency hidden behind compute
      const int kb1 = (kt + 1) << 6;
      const size_t kbase = kband + (size_t)kb1 * 1024;
      gk[0] = *(const bf16x8*)&kh_g[kbase + (size_t)r0 * 1024 + c0];
      gk[1] = *(const bf16x8*)&kh_g[kbase + (size_t)r1 * 1024 + c1];
      gk[2] = *(const bf16x8*)&kl_g[kbase + (size_t)r0 * 1024 + c0];
      gk[3] = *(const bf16x8*)&kl_g[kbase + (size_t)r1 * 1024 + c1];
      gk[4] = *(const bf16x8*)&vt_g[vtb + (size_t)r0 * 2048 + kb1 + c0];
      gk[5] = *(const bf16x8*)&vt_g[vtb + (size_t)r1 * 2048 + kb1 + c1];
    }

    bf16x8 bkh[4][2], bkl[4][2];
#pragma unroll
    for (int j = 0; j < 4; ++j)
#pragma unroll
      for (int s2 = 0; s2 < 2; ++s2) {
        bkh[j][s2] = *(const bf16x8*)&Kh[(j * 16 + c) * 72 + s2 * 32 + quad * 8];
        bkl[j][s2] = *(const bf16x8*)&Kl[(j * 16 + c) * 72 + s2 * 32 + quad * 8];
      }

    f32x4 s4[4];
#pragma unroll
    for (int j = 0; j < 4; ++j) s4[j] = fzero;
#pragma unroll
    for (int j = 0; j < 4; ++j)
#pragma unroll
      for (int s2 = 0; s2 < 2; ++s2) {
        s4[j] = __builtin_amdgcn_mfma_f32_16x16x32_bf16(aqh[s2], bkh[j][s2], s4[j], 0, 0, 0);
        s4[j] = __builtin_amdgcn_mfma_f32_16x16x32_bf16(aqh[s2], bkl[j][s2], s4[j], 0, 0, 0);
        s4[j] = __builtin_amdgcn_mfma_f32_16x16x32_bf16(aql[s2], bkh[j][s2], s4[j], 0, 0, 0);
      }

    if (kt == qt) {  // diagonal tile: strict-upper mask (t0 == kb)
#pragma unroll
      for (int j = 0; j < 4; ++j)
#pragma unroll
        for (int r = 0; r < 4; ++r)
          if (j * 16 + c > w * 16 + quad * 4 + r) s4[j][r] = -3e38f;
    }

    float p[4][4];
#pragma unroll
    for (int r = 0; r < 4; ++r) {
      float mt = fmaxf(fmaxf(s4[0][r], s4[1][r]), fmaxf(s4[2][r], s4[3][r]));
      mt = rowmax16(mt);  // DPP row reduce
      const float mn = fmaxf(m_i[r], mt);
      const float al = exp2f(m_i[r] - mn);  // logits already in log2 domain
      m_i[r] = mn;
#pragma unroll
      for (int j = 0; j < 4; ++j) p[r][j] = exp2f(s4[j][r] - mn);
      l4[r] *= al;
#pragma unroll
      for (int j = 0; j < 4; ++j) o[j][r] *= al;
    }

    // P -> wave-private region, stride 76 (conflict-free; intra-wave RAW only)
    bf16* Pw = Ps + w * 16 * 76;
#pragma unroll
    for (int r = 0; r < 4; ++r)
#pragma unroll
      for (int j = 0; j < 4; ++j)
        Pw[(quad * 4 + r) * 76 + j * 16 + c] = (bf16)p[r][j];

    bf16x8 ap[2], bv[4][2];
#pragma unroll
    for (int s2 = 0; s2 < 2; ++s2)
      ap[s2] = *(const bf16x8*)&Pw[c * 76 + s2 * 32 + quad * 8];
#pragma unroll
    for (int j = 0; j < 4; ++j)
#pragma unroll
      for (int s2 = 0; s2 < 2; ++s2)
        bv[j][s2] = *(const bf16x8*)&Vt[(j * 16 + c) * 72 + s2 * 32 + quad * 8];
    // l row-sum via MFMA (B = ones): D[m][n] = sum_k P[m][k], all n equal.
    l4 = __builtin_amdgcn_mfma_f32_16x16x32_bf16(ap[0], vone, l4, 0, 0, 0);
    l4 = __builtin_amdgcn_mfma_f32_16x16x32_bf16(ap[1], vone, l4, 0, 0, 0);
#pragma unroll
    for (int j = 0; j < 4; ++j)
#pragma unroll
      for (int s2 = 0; s2 < 2; ++s2)
        o[j] = __builtin_amdgcn_mfma_f32_16x16x32_bf16(ap[s2], bv[j][s2], o[j], 0, 0, 0);
  }

#pragma unroll
  for (int r = 0; r < 4; ++r) {
    const float inv = 1.0f / l4[r];
#pragma unroll
    for (int j = 0; j < 4; ++j) {
      const size_t oi =
          ((size_t)(b * 2048 + t0 + w * 16 + quad * 4 + r)) * 1024 + h * 64 +
          j * 16 + c;
      out[oi] = (bf16)(o[j][r] * inv);
    }
  }
}

// ---------------------------------------------------------------------------
// Workspace plan (80 MiB peak; >104 MiB previously corrupted harness memory):
//   [ 0, 8)   Wq|Wk|Wv|Wo bf16
//   [ 8,24)   h_hi|h_lo  -> (after gemm_qkv) Wf1_b|Wf2_b   (attn_cvt2 fills)
//   [24,40)   qh|ql      -> (after attn)   x1 (f32)
//   [40,72)   kh|kl|vt|attnout -> (after Wo) ff (bf16 4096x4096)
//   [72,80)   h2
// ---------------------------------------------------------------------------
extern "C" void kernel_launch(void* const* d_in, const int* in_sizes, int n_in,
                              void* d_out, int out_size, void* d_ws,
                              size_t ws_size, hipStream_t stream) {
  const float* x = (const float*)d_in[0];
  const float* g1 = (const float*)d_in[2];
  const float* b1 = (const float*)d_in[3];
  const float* g2 = (const float*)d_in[4];
  const float* b2 = (const float*)d_in[5];
  const float* Wq = (const float*)d_in[6];
  const float* Wk = (const float*)d_in[7];
  const float* Wv = (const float*)d_in[8];
  const float* Wo = (const float*)d_in[9];
  const float* Wf1 = (const float*)d_in[10];
  const float* Wf2 = (const float*)d_in[11];
  char* ws = (char*)d_ws;
  const size_t MB = 1024 * 1024;
  const size_t M1 = 1u << 20;
  bf16* Wq_b = (bf16*)ws;
  bf16* Wk_b = Wq_b + 1 * M1;
  bf16* Wv_b = Wq_b + 2 * M1;
  bf16* Wo_b = Wq_b + 3 * M1;
  bf16* h_hi = (bf16*)(ws + 8 * MB);
  bf16* h_lo = (bf16*)(ws + 16 * MB);
  bf16* Wf1_b = h_hi;  // alias: h dead after gemm_qkv; attn_cvt2 fills
  bf16* Wf2_b = h_lo;
  bf16* qh = (bf16*)(ws + 24 * MB);
  bf16* ql = (bf16*)(ws + 32 * MB);
  bf16* kh = (bf16*)(ws + 40 * MB);
  bf16* kl = (bf16*)(ws + 48 * MB);
  bf16* vt = (bf16*)(ws + 56 * MB);
  bf16* attnout = (bf16*)(ws + 64 * MB);
  float* x1 = (float*)qh;  // alias: qh/ql dead after attn
  bf16* h2 = (bf16*)(ws + 72 * MB);
  bf16* ff = kh;  // alias: kh/kl/vt/attnout dead after Wo GEMM
  float* outp = (float*)d_out;

  // 1) LN1 (split bf16 hi/lo) + cvt4 (attention weights) in one launch
  ln1_cvt4<<<8192, 256, 0, stream>>>(x, g1, b1, h_hi, h_lo, Wq, Wk, Wv, Wo,
                                     Wq_b);
  // 2) Q,K (merged split bf16, q scale = 1/8*log2e) + V^T fused
  gemm_qkv<<<dim3(24, 32), 256, 0, stream>>>(h_hi, h_lo, Wq_b, Wk_b, Wv_b, qh,
                                             ql, kh, kl, vt);
  // 3) attention (blocks 0..1023) + cvt2 FF weights (blocks 1024..9215)
  attn_cvt2<<<9216, 256, 0, stream>>>(qh, ql, kh, kl, vt, attnout, Wf1, Wf2,
                                      Wf1_b);
  // 4) x1 = x + attnout @ Wo^T   (f32; overwrites dead qh/ql) — 64N tiles
  gemm_bt64<2><<<dim3(16, 32), 256, 0, stream>>>(attnout, Wo_b, (void*)x1, x,
                                                 4096, 1024, 1024);
  // 5) LN2 -> h2 (bf16)
  ln_kernel<<<4096, 256, 0, stream>>>(x1, g2, b2, h2);
  // 6) ff = gelu(h2 @ Wff1^T)  (bf16; 128x64 tiles, BK=128)
  gemm_bt64<3><<<dim3(64, 32), 256, 0, stream>>>(h2, Wf1_b, (void*)ff, nullptr,
                                                 4096, 4096, 1024);
  // 7) out = x1 + ff @ Wff2^T  (f32) — 64N tiles
  gemm_bt64<2><<<dim3(16, 32), 256, 0, stream>>>(ff, Wf2_b, (void*)outp, x1,
                                                 4096, 1024, 4096);
}

// Round 8
// 395.560 us; speedup vs baseline: 1.0532x; 1.0316x over previous
//
#include <hip/hip_runtime.h>

typedef __bf16 bf16;
typedef bf16 bf16x8 __attribute__((ext_vector_type(8)));
typedef bf16 bf16x4 __attribute__((ext_vector_type(4)));
typedef float f32x4 __attribute__((ext_vector_type(4)));

// ---------------------------------------------------------------------------
// async global->LDS 16B copy (wave-uniform LDS base + lane*16 placement)
// ---------------------------------------------------------------------------
static __device__ __forceinline__ void async16(const void* g, void* l) {
  __builtin_amdgcn_global_load_lds((__attribute__((address_space(1))) void*)g,
                                   (__attribute__((address_space(3))) void*)l,
                                   16, 0, 0);
}

// DPP row_ror:N within 16-lane rows (VALU-only cross-lane; no LDS pipe).
template <int N>
static __device__ __forceinline__ float ror16(float x) {
  const int y =
      __builtin_amdgcn_update_dpp(0, __float_as_int(x), 0x120 | N, 0xf, 0xf, true);
  return __int_as_float(y);
}
static __device__ __forceinline__ float rowmax16(float x) {
  x = fmaxf(x, ror16<8>(x));
  x = fmaxf(x, ror16<4>(x));
  x = fmaxf(x, ror16<2>(x));
  x = fmaxf(x, ror16<1>(x));
  return x;
}

// ---------------------------------------------------------------------------
// LN1 (split bf16 hi/lo) fused with cvt4 (attention weights f32->bf16).
// blocks [0,4096): LN rows; blocks [4096,8192): weight conversion chunks.
// ---------------------------------------------------------------------------
__global__ __launch_bounds__(256) void ln1_cvt4(
    const float* __restrict__ x, const float* __restrict__ g,
    const float* __restrict__ b, bf16* __restrict__ hi, bf16* __restrict__ lo,
    const float* __restrict__ Wq, const float* __restrict__ Wk,
    const float* __restrict__ Wv, const float* __restrict__ Wo,
    bf16* __restrict__ wdst) {
  const int tid = threadIdx.x;
  if (blockIdx.x >= 4096) {  // cvt4 path
    const size_t i = ((size_t)(blockIdx.x - 4096) * 256 + tid) * 4;
    const size_t M1 = 1u << 20;
    const float* src = (i < M1) ? Wq : (i < 2 * M1) ? Wk : (i < 3 * M1) ? Wv : Wo;
    const size_t off = i & (M1 - 1);
    const float4 v = *(const float4*)(src + off);
    bf16x4 o = {(bf16)v.x, (bf16)v.y, (bf16)v.z, (bf16)v.w};
    *(bf16x4*)(wdst + i) = o;
    return;
  }
  const int row = blockIdx.x;
  const float* xr = x + (size_t)row * 1024;
  float v[4];
  float s1 = 0.f, s2 = 0.f;
#pragma unroll
  for (int j = 0; j < 4; ++j) {
    v[j] = xr[j * 256 + tid];
    s1 += v[j];
    s2 += v[j] * v[j];
  }
#pragma unroll
  for (int off = 1; off < 64; off <<= 1) {
    s1 += __shfl_xor(s1, off);
    s2 += __shfl_xor(s2, off);
  }
  __shared__ float ws1[4], ws2[4];
  const int wid = tid >> 6;
  if ((tid & 63) == 0) {
    ws1[wid] = s1;
    ws2[wid] = s2;
  }
  __syncthreads();
  s1 = ws1[0] + ws1[1] + ws1[2] + ws1[3];
  s2 = ws2[0] + ws2[1] + ws2[2] + ws2[3];
  const float mu = s1 * (1.f / 1024.f);
  const float var = s2 * (1.f / 1024.f) - mu * mu;
  const float rstd = 1.0f / sqrtf(var + 1e-5f);
#pragma unroll
  for (int j = 0; j < 4; ++j) {
    const int cc = j * 256 + tid;
    const float y = (v[j] - mu) * rstd * g[cc] + b[cc];
    const bf16 yh = (bf16)y;
    hi[(size_t)row * 1024 + cc] = yh;
    lo[(size_t)row * 1024 + cc] = (bf16)(y - (float)yh);
  }
}

// ---------------------------------------------------------------------------
// LayerNorm over D=1024 (f32 input), one block per row (non-split).
// ---------------------------------------------------------------------------
__global__ __launch_bounds__(256) void ln_kernel(
    const float* __restrict__ x, const float* __restrict__ g,
    const float* __restrict__ b, bf16* __restrict__ hi) {
  const int row = blockIdx.x;
  const int tid = threadIdx.x;
  const float* xr = x + (size_t)row * 1024;
  float v[4];
  float s1 = 0.f, s2 = 0.f;
#pragma unroll
  for (int j = 0; j < 4; ++j) {
    v[j] = xr[j * 256 + tid];
    s1 += v[j];
    s2 += v[j] * v[j];
  }
#pragma unroll
  for (int off = 1; off < 64; off <<= 1) {
    s1 += __shfl_xor(s1, off);
    s2 += __shfl_xor(s2, off);
  }
  __shared__ float ws1[4], ws2[4];
  const int wid = tid >> 6;
  if ((tid & 63) == 0) {
    ws1[wid] = s1;
    ws2[wid] = s2;
  }
  __syncthreads();
  s1 = ws1[0] + ws1[1] + ws1[2] + ws1[3];
  s2 = ws2[0] + ws2[1] + ws2[2] + ws2[3];
  const float mu = s1 * (1.f / 1024.f);
  const float var = s2 * (1.f / 1024.f) - mu * mu;
  const float rstd = 1.0f / sqrtf(var + 1e-5f);
#pragma unroll
  for (int j = 0; j < 4; ++j) {
    const int cc = j * 256 + tid;
    const float y = (v[j] - mu) * rstd * g[cc] + b[cc];
    hi[(size_t)row * 1024 + cc] = (bf16)y;
  }
}

// ---------------------------------------------------------------------------
// GEMM body: C[M,N] = A[M,K] * B[N,K]^T   (m97 structure, BK=64 as two BK=32
// sub-buffers per barrier pair). Used by gemm_qkv (EPI=5 V^T path).
// ---------------------------------------------------------------------------
template <int EPI>
static __device__ __forceinline__ void gemm_body(
    const bf16* __restrict__ A, const bf16* __restrict__ B,
    void* __restrict__ Cv, const float* __restrict__ R, bf16* smem, int col0,
    int row0, int M, int N, int K) {
  bf16* sA0 = smem;          // 128 x 32
  bf16* sA1 = smem + 4096;   // 128 x 32 (k+32)
  bf16* sB0 = smem + 8192;   // 128 x 32
  bf16* sB1 = smem + 12288;  // 128 x 32 (k+32)
  const int tid = threadIdx.x;
  const int lane = tid & 63;
  const int wid = tid >> 6;
  const int wm = wid >> 1, wn = wid & 1;

  f32x4 acc[4][4];
  const f32x4 fzero = {0.f, 0.f, 0.f, 0.f};
#pragma unroll
  for (int i = 0; i < 4; ++i)
#pragma unroll
    for (int j = 0; j < 4; ++j) acc[i][j] = fzero;

  const int nk = K >> 6;
  const int r0 = tid >> 2, c0 = (tid & 3) << 3;
  const int r1 = (256 + tid) >> 2, c1 = ((256 + tid) & 3) << 3;
  const int wofs0 = (wid << 6) * 8;  // wave-uniform LDS offsets
  const int wofs1 = (256 + (wid << 6)) * 8;

  for (int kt = 0; kt < nk; ++kt) {
    const int k0 = kt << 6;
    async16(A + (size_t)(row0 + r0) * K + k0 + c0, sA0 + wofs0);
    async16(A + (size_t)(row0 + r1) * K + k0 + c1, sA0 + wofs1);
    async16(A + (size_t)(row0 + r0) * K + k0 + 32 + c0, sA1 + wofs0);
    async16(A + (size_t)(row0 + r1) * K + k0 + 32 + c1, sA1 + wofs1);
    async16(B + (size_t)(col0 + r0) * K + k0 + c0, sB0 + wofs0);
    async16(B + (size_t)(col0 + r1) * K + k0 + c1, sB0 + wofs1);
    async16(B + (size_t)(col0 + r0) * K + k0 + 32 + c0, sB1 + wofs0);
    async16(B + (size_t)(col0 + r1) * K + k0 + 32 + c1, sB1 + wofs1);
    __syncthreads();
    const int fr = lane & 15, fq = (lane >> 4) << 3;
#pragma unroll
    for (int t = 0; t < 2; ++t) {
      const bf16* sA = t ? sA1 : sA0;
      const bf16* sB = t ? sB1 : sB0;
      bf16x8 af[4], bfr[4];
#pragma unroll
      for (int i = 0; i < 4; ++i)
        af[i] = *(const bf16x8*)&sA[(wm * 64 + i * 16 + fr) * 32 + fq];
#pragma unroll
      for (int j = 0; j < 4; ++j)
        bfr[j] = *(const bf16x8*)&sB[(wn * 64 + j * 16 + fr) * 32 + fq];
#pragma unroll
      for (int i = 0; i < 4; ++i)
#pragma unroll
        for (int j = 0; j < 4; ++j)
          acc[i][j] = __builtin_amdgcn_mfma_f32_16x16x32_bf16(
              af[i], bfr[j], acc[i][j], 0, 0, 0);
    }
    __syncthreads();
  }

  // C/D layout (m89-verified): col = lane&15, row = (lane>>4)*4 + reg
  const int fr = lane & 15, fq4 = (lane >> 4) << 2;
#pragma unroll
  for (int i = 0; i < 4; ++i) {
#pragma unroll
    for (int j = 0; j < 4; ++j) {
      const int rbase = row0 + wm * 64 + i * 16 + fq4;
      const int col = col0 + wn * 64 + j * 16 + fr;
      if constexpr (EPI == 5) {
        const int b = rbase >> 11, t = rbase & 2047;
        const int hh = col >> 6, d = col & 63;
        bf16x4 o4 = {(bf16)acc[i][j][0], (bf16)acc[i][j][1],
                     (bf16)acc[i][j][2], (bf16)acc[i][j][3]};
        *(bf16x4*)&((bf16*)Cv)[(((size_t)(b * 16 + hh)) * 64 + d) * 2048 + t] =
            o4;
      } else {
#pragma unroll
        for (int r = 0; r < 4; ++r) {
          const size_t idx = (size_t)(rbase + r) * N + col;
          const float val = acc[i][j][r];
          if constexpr (EPI == 0) {
            ((float*)Cv)[idx] = val;
          } else if constexpr (EPI == 2) {
            ((float*)Cv)[idx] = val + R[idx];
          } else {  // EPI == 3
            ((bf16*)Cv)[idx] =
                (bf16)(0.5f * val * (1.0f + erff(val * 0.7071067811865476f)));
          }
        }
      }
    }
  }
}

// ---------------------------------------------------------------------------
// Merged split-K GEMM for q/k (BK=64, two sub-steps per barrier): stages
// A_hi, A_lo AND B each k-step (B loaded ONCE). Split bf16 hi/lo epilogue.
// ---------------------------------------------------------------------------
static __device__ __forceinline__ void gemm_split_merged(
    const bf16* __restrict__ A, const bf16* __restrict__ A2,
    const bf16* __restrict__ B, bf16* __restrict__ Chi, bf16* __restrict__ Clo,
    bf16* smem, float scale, int col0, int row0) {
  constexpr int K = 1024, N = 1024;
  bf16* sAh0 = smem;           // 128 x 32
  bf16* sAh1 = smem + 4096;    // k+32
  bf16* sAl0 = smem + 8192;
  bf16* sAl1 = smem + 12288;
  bf16* sB0 = smem + 16384;
  bf16* sB1 = smem + 20480;
  const int tid = threadIdx.x;
  const int lane = tid & 63;
  const int wid = tid >> 6;
  const int wm = wid >> 1, wn = wid & 1;

  f32x4 acc[4][4];
  const f32x4 fzero = {0.f, 0.f, 0.f, 0.f};
#pragma unroll
  for (int i = 0; i < 4; ++i)
#pragma unroll
    for (int j = 0; j < 4; ++j) acc[i][j] = fzero;

  const int r0 = tid >> 2, c0 = (tid & 3) << 3;
  const int r1 = (256 + tid) >> 2, c1 = ((256 + tid) & 3) << 3;
  const int wofs0 = (wid << 6) * 8;
  const int wofs1 = (256 + (wid << 6)) * 8;

  for (int kt = 0; kt < 16; ++kt) {
    const int k0 = kt << 6;
    async16(A + (size_t)(row0 + r0) * K + k0 + c0, sAh0 + wofs0);
    async16(A + (size_t)(row0 + r1) * K + k0 + c1, sAh0 + wofs1);
    async16(A + (size_t)(row0 + r0) * K + k0 + 32 + c0, sAh1 + wofs0);
    async16(A + (size_t)(row0 + r1) * K + k0 + 32 + c1, sAh1 + wofs1);
    async16(A2 + (size_t)(row0 + r0) * K + k0 + c0, sAl0 + wofs0);
    async16(A2 + (size_t)(row0 + r1) * K + k0 + c1, sAl0 + wofs1);
    async16(A2 + (size_t)(row0 + r0) * K + k0 + 32 + c0, sAl1 + wofs0);
    async16(A2 + (size_t)(row0 + r1) * K + k0 + 32 + c1, sAl1 + wofs1);
    async16(B + (size_t)(col0 + r0) * K + k0 + c0, sB0 + wofs0);
    async16(B + (size_t)(col0 + r1) * K + k0 + c1, sB0 + wofs1);
    async16(B + (size_t)(col0 + r0) * K + k0 + 32 + c0, sB1 + wofs0);
    async16(B + (size_t)(col0 + r1) * K + k0 + 32 + c1, sB1 + wofs1);
    __syncthreads();
    const int fr = lane & 15, fq = (lane >> 4) << 3;
#pragma unroll
    for (int t = 0; t < 2; ++t) {
      const bf16* sAh = t ? sAh1 : sAh0;
      const bf16* sAl = t ? sAl1 : sAl0;
      const bf16* sB = t ? sB1 : sB0;
      bf16x8 ah[4], al[4], bfr[4];
#pragma unroll
      for (int i = 0; i < 4; ++i) {
        ah[i] = *(const bf16x8*)&sAh[(wm * 64 + i * 16 + fr) * 32 + fq];
        al[i] = *(const bf16x8*)&sAl[(wm * 64 + i * 16 + fr) * 32 + fq];
      }
#pragma unroll
      for (int j = 0; j < 4; ++j)
        bfr[j] = *(const bf16x8*)&sB[(wn * 64 + j * 16 + fr) * 32 + fq];
#pragma unroll
      for (int i = 0; i < 4; ++i)
#pragma unroll
        for (int j = 0; j < 4; ++j) {
          acc[i][j] = __builtin_amdgcn_mfma_f32_16x16x32_bf16(
              ah[i], bfr[j], acc[i][j], 0, 0, 0);
          acc[i][j] = __builtin_amdgcn_mfma_f32_16x16x32_bf16(
              al[i], bfr[j], acc[i][j], 0, 0, 0);
        }
    }
    __syncthreads();
  }

  const int fr = lane & 15, fq4 = (lane >> 4) << 2;
#pragma unroll
  for (int i = 0; i < 4; ++i)
#pragma unroll
    for (int j = 0; j < 4; ++j) {
      const int rbase = row0 + wm * 64 + i * 16 + fq4;
      const int col = col0 + wn * 64 + j * 16 + fr;
#pragma unroll
      for (int r = 0; r < 4; ++r) {
        const size_t idx = (size_t)(rbase + r) * N + col;
        const float vs = acc[i][j][r] * scale;
        const bf16 hi = (bf16)vs;
        Chi[idx] = hi;
        Clo[idx] = (bf16)(vs - (float)hi);
      }
    }
}

// Q,K,V fused: grid (24, 32). bx>>3: 0=q (merged split, scale folds 1/8 AND
// log2e for the exp2 softmax), 1=k (merged split), 2=v (single-pass bf16 h,
// transposed store). ONE shared buffer (49152 B) for both paths.
__global__ __launch_bounds__(256) void gemm_qkv(
    const bf16* __restrict__ A, const bf16* __restrict__ A2,
    const bf16* __restrict__ Bq, const bf16* __restrict__ Bk,
    const bf16* __restrict__ Bv, bf16* qh, bf16* ql, bf16* kh, bf16* kl,
    bf16* vt) {
  __shared__ bf16 smem[24576];
  const int which = blockIdx.x >> 3;
  const int col0 = (blockIdx.x & 7) * 128, row0 = blockIdx.y * 128;
  if (which == 2) {
    gemm_body<5>(A, Bv, (void*)vt, nullptr, smem, col0, row0, 4096, 1024,
                 1024);
  } else {
    gemm_split_merged(A, A2, which ? Bk : Bq, which ? kh : qh, which ? kl : ql,
                      smem, which ? 1.0f : 0.125f * 1.44269504088896f, col0,
                      row0);
  }
}

// ---------------------------------------------------------------------------
// 128x64-tile GEMM, r8 REWRITE: 2-phase double-buffered BK=64 (T3 minimum
// template). Old structure (r3-r7) was stage -> barrier -> compute -> barrier:
// zero load/compute overlap — every k-step ate the full global->LDS latency
// at the first barrier (FF1 measured ~310 TF). New: STAGE(next) issues
// BEFORE compute(cur); ONE barrier per k-step (compiler's vmcnt(0) drain at
// the barrier covers both the staged loads and read completion). Catalog:
// 1ph -> counted-phase = +28-41% (m196); 2ph ~= 92% of 8ph (m230).
// LDS: 2 x {A 128x64 = 16 KB, B 64x64 = 8 KB} = 48 KB (same as r7 -> same
// occupancy). Race audit: STAGE writes buf^1 while reads hit buf (disjoint);
// barrier orders swap.
// EPI: 0 = f32, 2 = f32(acc+R), 3 = bf16 gelu(acc).
// ---------------------------------------------------------------------------
template <int EPI>
__global__ __launch_bounds__(256) void gemm_bt64(
    const bf16* __restrict__ A, const bf16* __restrict__ B,
    void* __restrict__ Cv, const float* __restrict__ R, int M, int N, int K) {
  __shared__ bf16 smem[24576];  // 2 x {A0,A1: 4096 each; B0,B1: 2048 each}
  const int col0 = blockIdx.x * 64, row0 = blockIdx.y * 128;
  const int tid = threadIdx.x;
  const int lane = tid & 63;
  const int wid = tid >> 6;
  const int wm = wid >> 1, wn = wid & 1;

  f32x4 acc[4][2];
  const f32x4 fzero = {0.f, 0.f, 0.f, 0.f};
#pragma unroll
  for (int i = 0; i < 4; ++i)
#pragma unroll
    for (int j = 0; j < 2; ++j) acc[i][j] = fzero;

  const int nk = K >> 6;
  const int r0 = tid >> 2, c0 = (tid & 3) << 3;
  const int r1 = (256 + tid) >> 2, c1 = ((256 + tid) & 3) << 3;
  const int wofs0 = (wid << 6) * 8;
  const int wofs1 = (256 + (wid << 6)) * 8;

  auto stage = [&](int q, int kt) {
    const int k0 = kt << 6;
    bf16* base = smem + q * 12288;
    async16(A + (size_t)(row0 + r0) * K + k0 + c0, base + wofs0);
    async16(A + (size_t)(row0 + r1) * K + k0 + c1, base + wofs1);
    async16(A + (size_t)(row0 + r0) * K + k0 + 32 + c0, base + 4096 + wofs0);
    async16(A + (size_t)(row0 + r1) * K + k0 + 32 + c1, base + 4096 + wofs1);
    async16(B + (size_t)(col0 + r0) * K + k0 + c0, base + 8192 + wofs0);
    async16(B + (size_t)(col0 + r0) * K + k0 + 32 + c0, base + 10240 + wofs0);
  };

  stage(0, 0);
  __syncthreads();  // vmcnt(0) drain: buf0 ready
  int cur = 0;
  for (int kt = 0; kt < nk; ++kt) {
    if (kt + 1 < nk) stage(cur ^ 1, kt + 1);  // overlap with compute below
    const bf16* buf = smem + cur * 12288;
    const int fr = lane & 15, fq = (lane >> 4) << 3;
#pragma unroll
    for (int t = 0; t < 2; ++t) {
      const bf16* sA = buf + t * 4096;
      const bf16* sB = buf + 8192 + t * 2048;
      bf16x8 af[4], bfr[2];
#pragma unroll
      for (int i = 0; i < 4; ++i)
        af[i] = *(const bf16x8*)&sA[(wm * 64 + i * 16 + fr) * 32 + fq];
#pragma unroll
      for (int j = 0; j < 2; ++j)
        bfr[j] = *(const bf16x8*)&sB[(wn * 32 + j * 16 + fr) * 32 + fq];
#pragma unroll
      for (int i = 0; i < 4; ++i)
#pragma unroll
        for (int j = 0; j < 2; ++j)
          acc[i][j] = __builtin_amdgcn_mfma_f32_16x16x32_bf16(
              af[i], bfr[j], acc[i][j], 0, 0, 0);
    }
    __syncthreads();  // next buf staged + this buf's reads done
    cur ^= 1;
  }

  const int fr = lane & 15, fq4 = (lane >> 4) << 2;
#pragma unroll
  for (int i = 0; i < 4; ++i) {
#pragma unroll
    for (int j = 0; j < 2; ++j) {
      const int rbase = row0 + wm * 64 + i * 16 + fq4;
      const int col = col0 + wn * 32 + j * 16 + fr;
#pragma unroll
      for (int r = 0; r < 4; ++r) {
        const size_t idx = (size_t)(rbase + r) * N + col;
        const float val = acc[i][j][r];
        if constexpr (EPI == 3) {
          ((bf16*)Cv)[idx] =
              (bf16)(0.5f * val * (1.0f + erff(val * 0.7071067811865476f)));
        } else if constexpr (EPI == 2) {
          ((float*)Cv)[idx] = val + R[idx];
        } else {
          ((float*)Cv)[idx] = val;
        }
      }
    }
  }
}

// ---------------------------------------------------------------------------
// MFMA causal flash attention (64-query blocks) fused with cvt2
// (FF weights f32->bf16) in blocks [1024, 9216).
//  - logits in log2 domain (log2e folded into q scale) -> exp2f softmax
//  - Q fragments from global; next K/V tile register-prefetched
//  - 2 barriers/iter; P tile wave-private (stride 76, intra-wave RAW only)
//  - DPP rowmax softmax; LDS 37376 B -> 4 blocks/CU
//  - r1 POST-MORTEM: T5 setprio + T13 defer-rescale REGRESSED. DO NOT re-add.
//  - r4/r6: l = sum(P) via 2 extra MFMAs with B=ones — CONFIRMED WIN
//    (r6 A/B vs r3: 106.7 -> 103.3 us, VALUBusy 41.8 -> 39.7).
//  - LOCALITY INVARIANT (r4 post-mortem): bh must depend only on u=bid&255
//    (co-resident blocks share the K/V band). r4 broke this: dur +8%.
//  - r7 balanced-qt remap: NULL (103.3 -> 103.3, within noise) — the
//    per-CU qt-imbalance model didn't hold. Kept (harmless, bijective).
//    Per-wave work scaling also measured-fail (VGPR 148, occ 8.8%).
//    Attn plateau ~103 us: VALU 40%, MFMA 14%, latency/LDS-pipe rest.
//  - plain __launch_bounds__(256): (256,4) caused scratch spill — keep off
// ---------------------------------------------------------------------------
__global__ __launch_bounds__(256) void attn_cvt2(
    const bf16* __restrict__ qh_g, const bf16* __restrict__ ql_g,
    const bf16* __restrict__ kh_g, const bf16* __restrict__ kl_g,
    const bf16* __restrict__ vt_g, bf16* __restrict__ out,
    const float* __restrict__ Wf1, const float* __restrict__ Wf2,
    bf16* __restrict__ wdst) {
  __shared__ bf16 lds[18688];  // 37376 B
  const int tid = threadIdx.x;
  if (blockIdx.x >= 1024) {  // cvt2 path
    const size_t i = ((size_t)(blockIdx.x - 1024) * 256 + tid) * 4;
    const size_t M4 = 4u << 20;
    const float* src = (i < M4) ? Wf1 : Wf2;
    const size_t off = (i < M4) ? i : i - M4;
    const float4 v = *(const float4*)(src + off);
    bf16x4 o4 = {(bf16)v.x, (bf16)v.y, (bf16)v.z, (bf16)v.w};
    *(bf16x4*)(wdst + i) = o4;
    return;
  }
  bf16* Kh = lds;          // 64 x 72
  bf16* Kl = lds + 4608;   // 64 x 72
  bf16* Vt = lds + 9216;   // 64 x 72, rows = dim d, cols = key
  bf16* Ps = lds + 13824;  // 4 waves x 16 x 76 (wave-private)

  const int bid = blockIdx.x;
  // r7 mapping: bh depends only on u (locality invariant); qt balanced
  // across resident sets s. (Null vs r2 mapping; kept.)
  const int u = bid & 255;
  const int s = bid >> 8;        // resident-set index 0..3
  const int v = u >> 5;          // 0..7
  const int qbase = (3 - s) << 3;
  const int qt = qbase + ((s & 1) ? v : 7 - v);
  const int bh = (u & 7) * 4 + ((u >> 3) & 3);
  const int h = bh & 15;
  const int b = bh >> 4;
  const int t0 = qt << 6;
  const int w = tid >> 6;
  const int lane = tid & 63;
  const int c = lane & 15;
  const int quad = lane >> 4;

  const int r0 = tid >> 3, c0 = (tid & 7) << 3;
  const int r1 = (tid + 256) >> 3, c1 = ((tid + 256) & 7) << 3;

  // Q fragments straight from global (once per block)
  const size_t qrow =
      ((size_t)(b * 2048 + t0 + w * 16 + c)) * 1024 + h * 64 + quad * 8;
  bf16x8 aqh[2], aql[2];
  aqh[0] = *(const bf16x8*)&qh_g[qrow];
  aqh[1] = *(const bf16x8*)&qh_g[qrow + 32];
  aql[0] = *(const bf16x8*)&ql_g[qrow];
  aql[1] = *(const bf16x8*)&ql_g[qrow + 32];

  f32x4 o[4];
  const f32x4 fzero = {0.f, 0.f, 0.f, 0.f};
#pragma unroll
  for (int j = 0; j < 4; ++j) o[j] = fzero;
  f32x4 l4 = fzero;  // row-sum accumulator (MFMA with B=ones)
  float m_i[4] = {-3e38f, -3e38f, -3e38f, -3e38f};

  bf16x8 vone;
#pragma unroll
  for (int z = 0; z < 8; ++z) vone[z] = (bf16)1.0f;

  const size_t vtb = ((size_t)(b * 16 + h)) * 64 * 2048;  // + d*2048 + t
  const size_t kband = ((size_t)(b * 2048)) * 1024 + h * 64;

  bf16x8 gk[6];  // register prefetch of next K/V tile
  {
    gk[0] = *(const bf16x8*)&kh_g[kband + (size_t)r0 * 1024 + c0];
    gk[1] = *(const bf16x8*)&kh_g[kband + (size_t)r1 * 1024 + c1];
    gk[2] = *(const bf16x8*)&kl_g[kband + (size_t)r0 * 1024 + c0];
    gk[3] = *(const bf16x8*)&kl_g[kband + (size_t)r1 * 1024 + c1];
    gk[4] = *(const bf16x8*)&vt_g[vtb + (size_t)r0 * 2048 + c0];
    gk[5] = *(const bf16x8*)&vt_g[vtb + (size_t)r1 * 2048 + c1];
  }

  for (int kt = 0; kt <= qt; ++kt) {
    __syncthreads();  // (A) prev tile's fragment reads done before restage
    *(bf16x8*)&Kh[r0 * 72 + c0] = gk[0];
    *(bf16x8*)&Kh[r1 * 72 + c1] = gk[1];
    *(bf16x8*)&Kl[r0 * 72 + c0] = gk[2];
    *(bf16x8*)&Kl[r1 * 72 + c1] = gk[3];
    *(bf16x8*)&Vt[r0 * 72 + c0] = gk[4];
    *(bf16x8*)&Vt[r1 * 72 + c1] = gk[5];
    __syncthreads();  // (B) staging visible

    if (kt < qt) {  // prefetch next tile; latency hidden behind compute
      const int kb1 = (kt + 1) << 6;
      const size_t kbase = kband + (size_t)kb1 * 1024;
      gk[0] = *(const bf16x8*)&kh_g[kbase + (size_t)r0 * 1024 + c0];
      gk[1] = *(const bf16x8*)&kh_g[kbase + (size_t)r1 * 1024 + c1];
      gk[2] = *(const bf16x8*)&kl_g[kbase + (size_t)r0 * 1024 + c0];
      gk[3] = *(const bf16x8*)&kl_g[kbase + (size_t)r1 * 1024 + c1];
      gk[4] = *(const bf16x8*)&vt_g[vtb + (size_t)r0 * 2048 + kb1 + c0];
      gk[5] = *(const bf16x8*)&vt_g[vtb + (size_t)r1 * 2048 + kb1 + c1];
    }

    bf16x8 bkh[4][2], bkl[4][2];
#pragma unroll
    for (int j = 0; j < 4; ++j)
#pragma unroll
      for (int s2 = 0; s2 < 2; ++s2) {
        bkh[j][s2] = *(const bf16x8*)&Kh[(j * 16 + c) * 72 + s2 * 32 + quad * 8];
        bkl[j][s2] = *(const bf16x8*)&Kl[(j * 16 + c) * 72 + s2 * 32 + quad * 8];
      }

    f32x4 s4[4];
#pragma unroll
    for (int j = 0; j < 4; ++j) s4[j] = fzero;
#pragma unroll
    for (int j = 0; j < 4; ++j)
#pragma unroll
      for (int s2 = 0; s2 < 2; ++s2) {
        s4[j] = __builtin_amdgcn_mfma_f32_16x16x32_bf16(aqh[s2], bkh[j][s2], s4[j], 0, 0, 0);
        s4[j] = __builtin_amdgcn_mfma_f32_16x16x32_bf16(aqh[s2], bkl[j][s2], s4[j], 0, 0, 0);
        s4[j] = __builtin_amdgcn_mfma_f32_16x16x32_bf16(aql[s2], bkh[j][s2], s4[j], 0, 0, 0);
      }

    if (kt == qt) {  // diagonal tile: strict-upper mask (t0 == kb)
#pragma unroll
      for (int j = 0; j < 4; ++j)
#pragma unroll
        for (int r = 0; r < 4; ++r)
          if (j * 16 + c > w * 16 + quad * 4 + r) s4[j][r] = -3e38f;
    }

    float p[4][4];
#pragma unroll
    for (int r = 0; r < 4; ++r) {
      float mt = fmaxf(fmaxf(s4[0][r], s4[1][r]), fmaxf(s4[2][r], s4[3][r]));
      mt = rowmax16(mt);  // DPP row reduce
      const float mn = fmaxf(m_i[r], mt);
      const float al = exp2f(m_i[r] - mn);  // logits already in log2 domain
      m_i[r] = mn;
#pragma unroll
      for (int j = 0; j < 4; ++j) p[r][j] = exp2f(s4[j][r] - mn);
      l4[r] *= al;
#pragma unroll
      for (int j = 0; j < 4; ++j) o[j][r] *= al;
    }

    // P -> wave-private region, stride 76 (conflict-free; intra-wave RAW only)
    bf16* Pw = Ps + w * 16 * 76;
#pragma unroll
    for (int r = 0; r < 4; ++r)
#pragma unroll
      for (int j = 0; j < 4; ++j)
        Pw[(quad * 4 + r) * 76 + j * 16 + c] = (bf16)p[r][j];

    bf16x8 ap[2], bv[4][2];
#pragma unroll
    for (int s2 = 0; s2 < 2; ++s2)
      ap[s2] = *(const bf16x8*)&Pw[c * 76 + s2 * 32 + quad * 8];
#pragma unroll
    for (int j = 0; j < 4; ++j)
#pragma unroll
      for (int s2 = 0; s2 < 2; ++s2)
        bv[j][s2] = *(const bf16x8*)&Vt[(j * 16 + c) * 72 + s2 * 32 + quad * 8];
    // l row-sum via MFMA (B = ones): D[m][n] = sum_k P[m][k], all n equal.
    l4 = __builtin_amdgcn_mfma_f32_16x16x32_bf16(ap[0], vone, l4, 0, 0, 0);
    l4 = __builtin_amdgcn_mfma_f32_16x16x32_bf16(ap[1], vone, l4, 0, 0, 0);
#pragma unroll
    for (int j = 0; j < 4; ++j)
#pragma unroll
      for (int s2 = 0; s2 < 2; ++s2)
        o[j] = __builtin_amdgcn_mfma_f32_16x16x32_bf16(ap[s2], bv[j][s2], o[j], 0, 0, 0);
  }

#pragma unroll
  for (int r = 0; r < 4; ++r) {
    const float inv = 1.0f / l4[r];
#pragma unroll
    for (int j = 0; j < 4; ++j) {
      const size_t oi =
          ((size_t)(b * 2048 + t0 + w * 16 + quad * 4 + r)) * 1024 + h * 64 +
          j * 16 + c;
      out[oi] = (bf16)(o[j][r] * inv);
    }
  }
}

// ---------------------------------------------------------------------------
// Workspace plan (80 MiB peak; >104 MiB previously corrupted harness memory):
//   [ 0, 8)   Wq|Wk|Wv|Wo bf16
//   [ 8,24)   h_hi|h_lo  -> (after gemm_qkv) Wf1_b|Wf2_b   (attn_cvt2 fills)
//   [24,40)   qh|ql      -> (after attn)   x1 (f32)
//   [40,72)   kh|kl|vt|attnout -> (after Wo) ff (bf16 4096x4096)
//   [72,80)   h2
// ---------------------------------------------------------------------------
extern "C" void kernel_launch(void* const* d_in, const int* in_sizes, int n_in,
                              void* d_out, int out_size, void* d_ws,
                              size_t ws_size, hipStream_t stream) {
  const float* x = (const float*)d_in[0];
  const float* g1 = (const float*)d_in[2];
  const float* b1 = (const float*)d_in[3];
  const float* g2 = (const float*)d_in[4];
  const float* b2 = (const float*)d_in[5];
  const float* Wq = (const float*)d_in[6];
  const float* Wk = (const float*)d_in[7];
  const float* Wv = (const float*)d_in[8];
  const float* Wo = (const float*)d_in[9];
  const float* Wf1 = (const float*)d_in[10];
  const float* Wf2 = (const float*)d_in[11];
  char* ws = (char*)d_ws;
  const size_t MB = 1024 * 1024;
  const size_t M1 = 1u << 20;
  bf16* Wq_b = (bf16*)ws;
  bf16* Wk_b = Wq_b + 1 * M1;
  bf16* Wv_b = Wq_b + 2 * M1;
  bf16* Wo_b = Wq_b + 3 * M1;
  bf16* h_hi = (bf16*)(ws + 8 * MB);
  bf16* h_lo = (bf16*)(ws + 16 * MB);
  bf16* Wf1_b = h_hi;  // alias: h dead after gemm_qkv; attn_cvt2 fills
  bf16* Wf2_b = h_lo;
  bf16* qh = (bf16*)(ws + 24 * MB);
  bf16* ql = (bf16*)(ws + 32 * MB);
  bf16* kh = (bf16*)(ws + 40 * MB);
  bf16* kl = (bf16*)(ws + 48 * MB);
  bf16* vt = (bf16*)(ws + 56 * MB);
  bf16* attnout = (bf16*)(ws + 64 * MB);
  float* x1 = (float*)qh;  // alias: qh/ql dead after attn
  bf16* h2 = (bf16*)(ws + 72 * MB);
  bf16* ff = kh;  // alias: kh/kl/vt/attnout dead after Wo GEMM
  float* outp = (float*)d_out;

  // 1) LN1 (split bf16 hi/lo) + cvt4 (attention weights) in one launch
  ln1_cvt4<<<8192, 256, 0, stream>>>(x, g1, b1, h_hi, h_lo, Wq, Wk, Wv, Wo,
                                     Wq_b);
  // 2) Q,K (merged split bf16, q scale = 1/8*log2e) + V^T fused
  gemm_qkv<<<dim3(24, 32), 256, 0, stream>>>(h_hi, h_lo, Wq_b, Wk_b, Wv_b, qh,
                                             ql, kh, kl, vt);
  // 3) attention (blocks 0..1023) + cvt2 FF weights (blocks 1024..9215)
  attn_cvt2<<<9216, 256, 0, stream>>>(qh, ql, kh, kl, vt, attnout, Wf1, Wf2,
                                      Wf1_b);
  // 4) x1 = x + attnout @ Wo^T   (f32; overwrites dead qh/ql) — 64N tiles
  gemm_bt64<2><<<dim3(16, 32), 256, 0, stream>>>(attnout, Wo_b, (void*)x1, x,
                                                 4096, 1024, 1024);
  // 5) LN2 -> h2 (bf16)
  ln_kernel<<<4096, 256, 0, stream>>>(x1, g2, b2, h2);
  // 6) ff = gelu(h2 @ Wff1^T)  (bf16; 128x64 tiles, 2-phase dbuf BK=64)
  gemm_bt64<3><<<dim3(64, 32), 256, 0, stream>>>(h2, Wf1_b, (void*)ff, nullptr,
                                                 4096, 4096, 1024);
  // 7) out = x1 + ff @ Wff2^T  (f32) — 64N tiles
  gemm_bt64<2><<<dim3(16, 32), 256, 0, stream>>>(ff, Wf2_b, (void*)outp, x1,
                                                 4096, 1024, 4096);
}

// Round 10
// 388.492 us; speedup vs baseline: 1.0723x; 1.0182x over previous
//
#include <hip/hip_runtime.h>

typedef __bf16 bf16;
typedef bf16 bf16x8 __attribute__((ext_vector_type(8)));
typedef bf16 bf16x4 __attribute__((ext_vector_type(4)));
typedef float f32x4 __attribute__((ext_vector_type(4)));

// ---------------------------------------------------------------------------
// async global->LDS 16B copy (wave-uniform LDS base + lane*16 placement)
// ---------------------------------------------------------------------------
static __device__ __forceinline__ void async16(const void* g, void* l) {
  __builtin_amdgcn_global_load_lds((__attribute__((address_space(1))) void*)g,
                                   (__attribute__((address_space(3))) void*)l,
                                   16, 0, 0);
}

// DPP row_ror:N within 16-lane rows (VALU-only cross-lane; no LDS pipe).
template <int N>
static __device__ __forceinline__ float ror16(float x) {
  const int y =
      __builtin_amdgcn_update_dpp(0, __float_as_int(x), 0x120 | N, 0xf, 0xf, true);
  return __int_as_float(y);
}
static __device__ __forceinline__ float rowmax16(float x) {
  x = fmaxf(x, ror16<8>(x));
  x = fmaxf(x, ror16<4>(x));
  x = fmaxf(x, ror16<2>(x));
  x = fmaxf(x, ror16<1>(x));
  return x;
}

// ---------------------------------------------------------------------------
// LN1 (split bf16 hi/lo) fused with cvt4 (attention weights f32->bf16).
// blocks [0,4096): LN rows; blocks [4096,8192): weight conversion chunks.
// ---------------------------------------------------------------------------
__global__ __launch_bounds__(256) void ln1_cvt4(
    const float* __restrict__ x, const float* __restrict__ g,
    const float* __restrict__ b, bf16* __restrict__ hi, bf16* __restrict__ lo,
    const float* __restrict__ Wq, const float* __restrict__ Wk,
    const float* __restrict__ Wv, const float* __restrict__ Wo,
    bf16* __restrict__ wdst) {
  const int tid = threadIdx.x;
  if (blockIdx.x >= 4096) {  // cvt4 path
    const size_t i = ((size_t)(blockIdx.x - 4096) * 256 + tid) * 4;
    const size_t M1 = 1u << 20;
    const float* src = (i < M1) ? Wq : (i < 2 * M1) ? Wk : (i < 3 * M1) ? Wv : Wo;
    const size_t off = i & (M1 - 1);
    const float4 v = *(const float4*)(src + off);
    bf16x4 o = {(bf16)v.x, (bf16)v.y, (bf16)v.z, (bf16)v.w};
    *(bf16x4*)(wdst + i) = o;
    return;
  }
  const int row = blockIdx.x;
  const float* xr = x + (size_t)row * 1024;
  float v[4];
  float s1 = 0.f, s2 = 0.f;
#pragma unroll
  for (int j = 0; j < 4; ++j) {
    v[j] = xr[j * 256 + tid];
    s1 += v[j];
    s2 += v[j] * v[j];
  }
#pragma unroll
  for (int off = 1; off < 64; off <<= 1) {
    s1 += __shfl_xor(s1, off);
    s2 += __shfl_xor(s2, off);
  }
  __shared__ float ws1[4], ws2[4];
  const int wid = tid >> 6;
  if ((tid & 63) == 0) {
    ws1[wid] = s1;
    ws2[wid] = s2;
  }
  __syncthreads();
  s1 = ws1[0] + ws1[1] + ws1[2] + ws1[3];
  s2 = ws2[0] + ws2[1] + ws2[2] + ws2[3];
  const float mu = s1 * (1.f / 1024.f);
  const float var = s2 * (1.f / 1024.f) - mu * mu;
  const float rstd = 1.0f / sqrtf(var + 1e-5f);
#pragma unroll
  for (int j = 0; j < 4; ++j) {
    const int cc = j * 256 + tid;
    const float y = (v[j] - mu) * rstd * g[cc] + b[cc];
    const bf16 yh = (bf16)y;
    hi[(size_t)row * 1024 + cc] = yh;
    lo[(size_t)row * 1024 + cc] = (bf16)(y - (float)yh);
  }
}

// ---------------------------------------------------------------------------
// LayerNorm over D=1024 (f32 input), one block per row (non-split).
// ---------------------------------------------------------------------------
__global__ __launch_bounds__(256) void ln_kernel(
    const float* __restrict__ x, const float* __restrict__ g,
    const float* __restrict__ b, bf16* __restrict__ hi) {
  const int row = blockIdx.x;
  const int tid = threadIdx.x;
  const float* xr = x + (size_t)row * 1024;
  float v[4];
  float s1 = 0.f, s2 = 0.f;
#pragma unroll
  for (int j = 0; j < 4; ++j) {
    v[j] = xr[j * 256 + tid];
    s1 += v[j];
    s2 += v[j] * v[j];
  }
#pragma unroll
  for (int off = 1; off < 64; off <<= 1) {
    s1 += __shfl_xor(s1, off);
    s2 += __shfl_xor(s2, off);
  }
  __shared__ float ws1[4], ws2[4];
  const int wid = tid >> 6;
  if ((tid & 63) == 0) {
    ws1[wid] = s1;
    ws2[wid] = s2;
  }
  __syncthreads();
  s1 = ws1[0] + ws1[1] + ws1[2] + ws1[3];
  s2 = ws2[0] + ws2[1] + ws2[2] + ws2[3];
  const float mu = s1 * (1.f / 1024.f);
  const float var = s2 * (1.f / 1024.f) - mu * mu;
  const float rstd = 1.0f / sqrtf(var + 1e-5f);
#pragma unroll
  for (int j = 0; j < 4; ++j) {
    const int cc = j * 256 + tid;
    const float y = (v[j] - mu) * rstd * g[cc] + b[cc];
    hi[(size_t)row * 1024 + cc] = (bf16)y;
  }
}

// ---------------------------------------------------------------------------
// GEMM body: C[M,N] = A[M,K] * B[N,K]^T — r9 REWRITE: 2-phase double-buffered
// BK=32 (same structure as r8's gemm_bt64, which was +verified). LDS
// footprint unchanged vs old BK=64 two-sub-buffer version (2 x {A 8K, B 8K}
// = 32 KB). STAGE(next) issues before compute(cur); ONE barrier per k-step.
// Used by gemm_qkv (EPI=5 V^T path).
// ---------------------------------------------------------------------------
template <int EPI>
static __device__ __forceinline__ void gemm_body(
    const bf16* __restrict__ A, const bf16* __restrict__ B,
    void* __restrict__ Cv, const float* __restrict__ R, bf16* smem, int col0,
    int row0, int M, int N, int K) {
  const int tid = threadIdx.x;
  const int lane = tid & 63;
  const int wid = tid >> 6;
  const int wm = wid >> 1, wn = wid & 1;

  f32x4 acc[4][4];
  const f32x4 fzero = {0.f, 0.f, 0.f, 0.f};
#pragma unroll
  for (int i = 0; i < 4; ++i)
#pragma unroll
    for (int j = 0; j < 4; ++j) acc[i][j] = fzero;

  const int nk = K >> 5;
  const int r0 = tid >> 2, c0 = (tid & 3) << 3;
  const int r1 = (256 + tid) >> 2, c1 = ((256 + tid) & 3) << 3;
  const int wofs0 = (wid << 6) * 8;  // wave-uniform LDS offsets
  const int wofs1 = (256 + (wid << 6)) * 8;

  auto stage = [&](int q, int kt) {
    const int k0 = kt << 5;
    bf16* base = smem + q * 8192;  // A: 4096 bf16, B: 4096 bf16
    async16(A + (size_t)(row0 + r0) * K + k0 + c0, base + wofs0);
    async16(A + (size_t)(row0 + r1) * K + k0 + c1, base + wofs1);
    async16(B + (size_t)(col0 + r0) * K + k0 + c0, base + 4096 + wofs0);
    async16(B + (size_t)(col0 + r1) * K + k0 + c1, base + 4096 + wofs1);
  };

  stage(0, 0);
  __syncthreads();  // vmcnt(0) drain: buf0 ready
  int cur = 0;
  for (int kt = 0; kt < nk; ++kt) {
    if (kt + 1 < nk) stage(cur ^ 1, kt + 1);  // overlap with compute
    const bf16* buf = smem + cur * 8192;
    const int fr = lane & 15, fq = (lane >> 4) << 3;
    bf16x8 af[4], bfr[4];
#pragma unroll
    for (int i = 0; i < 4; ++i)
      af[i] = *(const bf16x8*)&buf[(wm * 64 + i * 16 + fr) * 32 + fq];
#pragma unroll
    for (int j = 0; j < 4; ++j)
      bfr[j] = *(const bf16x8*)&buf[4096 + (wn * 64 + j * 16 + fr) * 32 + fq];
#pragma unroll
    for (int i = 0; i < 4; ++i)
#pragma unroll
      for (int j = 0; j < 4; ++j)
        acc[i][j] = __builtin_amdgcn_mfma_f32_16x16x32_bf16(
            af[i], bfr[j], acc[i][j], 0, 0, 0);
    __syncthreads();  // next buf staged + this buf's reads done
    cur ^= 1;
  }

  // C/D layout (m89-verified): col = lane&15, row = (lane>>4)*4 + reg
  const int fr = lane & 15, fq4 = (lane >> 4) << 2;
#pragma unroll
  for (int i = 0; i < 4; ++i) {
#pragma unroll
    for (int j = 0; j < 4; ++j) {
      const int rbase = row0 + wm * 64 + i * 16 + fq4;
      const int col = col0 + wn * 64 + j * 16 + fr;
      if constexpr (EPI == 5) {
        const int b = rbase >> 11, t = rbase & 2047;
        const int hh = col >> 6, d = col & 63;
        bf16x4 o4 = {(bf16)acc[i][j][0], (bf16)acc[i][j][1],
                     (bf16)acc[i][j][2], (bf16)acc[i][j][3]};
        *(bf16x4*)&((bf16*)Cv)[(((size_t)(b * 16 + hh)) * 64 + d) * 2048 + t] =
            o4;
      } else {
#pragma unroll
        for (int r = 0; r < 4; ++r) {
          const size_t idx = (size_t)(rbase + r) * N + col;
          const float val = acc[i][j][r];
          if constexpr (EPI == 0) {
            ((float*)Cv)[idx] = val;
          } else if constexpr (EPI == 2) {
            ((float*)Cv)[idx] = val + R[idx];
          } else {  // EPI == 3
            ((bf16*)Cv)[idx] =
                (bf16)(0.5f * val * (1.0f + erff(val * 0.7071067811865476f)));
          }
        }
      }
    }
  }
}

// ---------------------------------------------------------------------------
// Merged split-K GEMM for q/k — r9 REWRITE: 2-phase double-buffered BK=32.
// Stages A_hi, A_lo AND B each k-step (B loaded ONCE); 2 x {Ah 8K, Al 8K,
// B 8K} = 48 KB = same LDS as the old BK=64 layout -> occupancy unchanged.
// Split bf16 hi/lo epilogue.
// ---------------------------------------------------------------------------
static __device__ __forceinline__ void gemm_split_merged(
    const bf16* __restrict__ A, const bf16* __restrict__ A2,
    const bf16* __restrict__ B, bf16* __restrict__ Chi, bf16* __restrict__ Clo,
    bf16* smem, float scale, int col0, int row0) {
  constexpr int K = 1024, N = 1024;
  const int tid = threadIdx.x;
  const int lane = tid & 63;
  const int wid = tid >> 6;
  const int wm = wid >> 1, wn = wid & 1;

  f32x4 acc[4][4];
  const f32x4 fzero = {0.f, 0.f, 0.f, 0.f};
#pragma unroll
  for (int i = 0; i < 4; ++i)
#pragma unroll
    for (int j = 0; j < 4; ++j) acc[i][j] = fzero;

  const int r0 = tid >> 2, c0 = (tid & 3) << 3;
  const int r1 = (256 + tid) >> 2, c1 = ((256 + tid) & 3) << 3;
  const int wofs0 = (wid << 6) * 8;
  const int wofs1 = (256 + (wid << 6)) * 8;

  auto stage = [&](int q, int kt) {
    const int k0 = kt << 5;
    bf16* base = smem + q * 12288;  // Ah 4096, Al 4096, B 4096 (bf16 counts)
    async16(A + (size_t)(row0 + r0) * K + k0 + c0, base + wofs0);
    async16(A + (size_t)(row0 + r1) * K + k0 + c1, base + wofs1);
    async16(A2 + (size_t)(row0 + r0) * K + k0 + c0, base + 4096 + wofs0);
    async16(A2 + (size_t)(row0 + r1) * K + k0 + c1, base + 4096 + wofs1);
    async16(B + (size_t)(col0 + r0) * K + k0 + c0, base + 8192 + wofs0);
    async16(B + (size_t)(col0 + r1) * K + k0 + c1, base + 8192 + wofs1);
  };

  stage(0, 0);
  __syncthreads();  // vmcnt(0) drain: buf0 ready
  int cur = 0;
  for (int kt = 0; kt < 32; ++kt) {
    if (kt + 1 < 32) stage(cur ^ 1, kt + 1);  // overlap with compute
    const bf16* base = smem + cur * 12288;
    const int fr = lane & 15, fq = (lane >> 4) << 3;
    bf16x8 ah[4], al[4], bfr[4];
#pragma unroll
    for (int i = 0; i < 4; ++i) {
      ah[i] = *(const bf16x8*)&base[(wm * 64 + i * 16 + fr) * 32 + fq];
      al[i] = *(const bf16x8*)&base[4096 + (wm * 64 + i * 16 + fr) * 32 + fq];
    }
#pragma unroll
    for (int j = 0; j < 4; ++j)
      bfr[j] = *(const bf16x8*)&base[8192 + (wn * 64 + j * 16 + fr) * 32 + fq];
#pragma unroll
    for (int i = 0; i < 4; ++i)
#pragma unroll
      for (int j = 0; j < 4; ++j) {
        acc[i][j] = __builtin_amdgcn_mfma_f32_16x16x32_bf16(
            ah[i], bfr[j], acc[i][j], 0, 0, 0);
        acc[i][j] = __builtin_amdgcn_mfma_f32_16x16x32_bf16(
            al[i], bfr[j], acc[i][j], 0, 0, 0);
      }
    __syncthreads();  // next buf staged + this buf's reads done
    cur ^= 1;
  }

  const int fr = lane & 15, fq4 = (lane >> 4) << 2;
#pragma unroll
  for (int i = 0; i < 4; ++i)
#pragma unroll
    for (int j = 0; j < 4; ++j) {
      const int rbase = row0 + wm * 64 + i * 16 + fq4;
      const int col = col0 + wn * 64 + j * 16 + fr;
#pragma unroll
      for (int r = 0; r < 4; ++r) {
        const size_t idx = (size_t)(rbase + r) * N + col;
        const float vs = acc[i][j][r] * scale;
        const bf16 hi = (bf16)vs;
        Chi[idx] = hi;
        Clo[idx] = (bf16)(vs - (float)hi);
      }
    }
}

// Q,K,V fused: grid (24, 32). bx>>3: 0=q (merged split, scale folds 1/8 AND
// log2e for the exp2 softmax), 1=k (merged split), 2=v (single-pass bf16 h,
// transposed store). ONE shared buffer (49152 B) for both paths.
__global__ __launch_bounds__(256) void gemm_qkv(
    const bf16* __restrict__ A, const bf16* __restrict__ A2,
    const bf16* __restrict__ Bq, const bf16* __restrict__ Bk,
    const bf16* __restrict__ Bv, bf16* qh, bf16* ql, bf16* kh, bf16* kl,
    bf16* vt) {
  __shared__ bf16 smem[24576];
  const int which = blockIdx.x >> 3;
  const int col0 = (blockIdx.x & 7) * 128, row0 = blockIdx.y * 128;
  if (which == 2) {
    gemm_body<5>(A, Bv, (void*)vt, nullptr, smem, col0, row0, 4096, 1024,
                 1024);
  } else {
    gemm_split_merged(A, A2, which ? Bk : Bq, which ? kh : qh, which ? kl : ql,
                      smem, which ? 1.0f : 0.125f * 1.44269504088896f, col0,
                      row0);
  }
}

// ---------------------------------------------------------------------------
// 128x64-tile GEMM, r8: 2-phase double-buffered BK=64 (T3 minimum template).
// CONFIRMED WIN r8: total 408 -> 395.6 (FF1/Wo/FF2 family). STAGE(next)
// issues BEFORE compute(cur); ONE barrier per k-step. LDS 48 KB.
// EPI: 0 = f32, 2 = f32(acc+R), 3 = bf16 gelu(acc).
// ---------------------------------------------------------------------------
template <int EPI>
__global__ __launch_bounds__(256) void gemm_bt64(
    const bf16* __restrict__ A, const bf16* __restrict__ B,
    void* __restrict__ Cv, const float* __restrict__ R, int M, int N, int K) {
  __shared__ bf16 smem[24576];  // 2 x {A0,A1: 4096 each; B0,B1: 2048 each}
  const int col0 = blockIdx.x * 64, row0 = blockIdx.y * 128;
  const int tid = threadIdx.x;
  const int lane = tid & 63;
  const int wid = tid >> 6;
  const int wm = wid >> 1, wn = wid & 1;

  f32x4 acc[4][2];
  const f32x4 fzero = {0.f, 0.f, 0.f, 0.f};
#pragma unroll
  for (int i = 0; i < 4; ++i)
#pragma unroll
    for (int j = 0; j < 2; ++j) acc[i][j] = fzero;

  const int nk = K >> 6;
  const int r0 = tid >> 2, c0 = (tid & 3) << 3;
  const int r1 = (256 + tid) >> 2, c1 = ((256 + tid) & 3) << 3;
  const int wofs0 = (wid << 6) * 8;
  const int wofs1 = (256 + (wid << 6)) * 8;

  auto stage = [&](int q, int kt) {
    const int k0 = kt << 6;
    bf16* base = smem + q * 12288;
    async16(A + (size_t)(row0 + r0) * K + k0 + c0, base + wofs0);
    async16(A + (size_t)(row0 + r1) * K + k0 + c1, base + wofs1);
    async16(A + (size_t)(row0 + r0) * K + k0 + 32 + c0, base + 4096 + wofs0);
    async16(A + (size_t)(row0 + r1) * K + k0 + 32 + c1, base + 4096 + wofs1);
    async16(B + (size_t)(col0 + r0) * K + k0 + c0, base + 8192 + wofs0);
    async16(B + (size_t)(col0 + r0) * K + k0 + 32 + c0, base + 10240 + wofs0);
  };

  stage(0, 0);
  __syncthreads();  // vmcnt(0) drain: buf0 ready
  int cur = 0;
  for (int kt = 0; kt < nk; ++kt) {
    if (kt + 1 < nk) stage(cur ^ 1, kt + 1);  // overlap with compute below
    const bf16* buf = smem + cur * 12288;
    const int fr = lane & 15, fq = (lane >> 4) << 3;
#pragma unroll
    for (int t = 0; t < 2; ++t) {
      const bf16* sA = buf + t * 4096;
      const bf16* sB = buf + 8192 + t * 2048;
      bf16x8 af[4], bfr[2];
#pragma unroll
      for (int i = 0; i < 4; ++i)
        af[i] = *(const bf16x8*)&sA[(wm * 64 + i * 16 + fr) * 32 + fq];
#pragma unroll
      for (int j = 0; j < 2; ++j)
        bfr[j] = *(const bf16x8*)&sB[(wn * 32 + j * 16 + fr) * 32 + fq];
#pragma unroll
      for (int i = 0; i < 4; ++i)
#pragma unroll
        for (int j = 0; j < 2; ++j)
          acc[i][j] = __builtin_amdgcn_mfma_f32_16x16x32_bf16(
              af[i], bfr[j], acc[i][j], 0, 0, 0);
    }
    __syncthreads();  // next buf staged + this buf's reads done
    cur ^= 1;
  }

  const int fr = lane & 15, fq4 = (lane >> 4) << 2;
#pragma unroll
  for (int i = 0; i < 4; ++i) {
#pragma unroll
    for (int j = 0; j < 2; ++j) {
      const int rbase = row0 + wm * 64 + i * 16 + fq4;
      const int col = col0 + wn * 32 + j * 16 + fr;
#pragma unroll
      for (int r = 0; r < 4; ++r) {
        const size_t idx = (size_t)(rbase + r) * N + col;
        const float val = acc[i][j][r];
        if constexpr (EPI == 3) {
          ((bf16*)Cv)[idx] =
              (bf16)(0.5f * val * (1.0f + erff(val * 0.7071067811865476f)));
        } else if constexpr (EPI == 2) {
          ((float*)Cv)[idx] = val + R[idx];
        } else {
          ((float*)Cv)[idx] = val;
        }
      }
    }
  }
}

// ---------------------------------------------------------------------------
// MFMA causal flash attention (64-query blocks) fused with cvt2
// (FF weights f32->bf16) in blocks [1024, 9216).
//  - logits in log2 domain (log2e folded into q scale) -> exp2f softmax
//  - Q fragments from global; next K/V tile register-prefetched
//  - 2 barriers/iter; P tile wave-private (stride 76, intra-wave RAW only)
//  - DPP rowmax softmax; LDS 37376 B -> 4 blocks/CU
//  - r1 POST-MORTEM: T5 setprio + T13 defer-rescale REGRESSED. DO NOT re-add.
//  - r4/r6: l = sum(P) via 2 extra MFMAs with B=ones — CONFIRMED WIN
//    (r6 A/B vs r3: 106.7 -> 103.3 us, VALUBusy 41.8 -> 39.7).
//  - LOCALITY INVARIANT (r4 post-mortem): bh must depend only on u=bid&255
//    (co-resident blocks share the K/V band). r4 broke this: dur +8%.
//  - r7 balanced-qt remap: NULL (kept, harmless). Per-wave work scaling
//    measured-fail (VGPR 148, occ 8.8%). Attn plateau ~103 us.
//  - plain __launch_bounds__(256): (256,4) caused scratch spill — keep off
// ---------------------------------------------------------------------------
__global__ __launch_bounds__(256) void attn_cvt2(
    const bf16* __restrict__ qh_g, const bf16* __restrict__ ql_g,
    const bf16* __restrict__ kh_g, const bf16* __restrict__ kl_g,
    const bf16* __restrict__ vt_g, bf16* __restrict__ out,
    const float* __restrict__ Wf1, const float* __restrict__ Wf2,
    bf16* __restrict__ wdst) {
  __shared__ bf16 lds[18688];  // 37376 B
  const int tid = threadIdx.x;
  if (blockIdx.x >= 1024) {  // cvt2 path
    const size_t i = ((size_t)(blockIdx.x - 1024) * 256 + tid) * 4;
    const size_t M4 = 4u << 20;
    const float* src = (i < M4) ? Wf1 : Wf2;
    const size_t off = (i < M4) ? i : i - M4;
    const float4 v = *(const float4*)(src + off);
    bf16x4 o4 = {(bf16)v.x, (bf16)v.y, (bf16)v.z, (bf16)v.w};
    *(bf16x4*)(wdst + i) = o4;
    return;
  }
  bf16* Kh = lds;          // 64 x 72
  bf16* Kl = lds + 4608;   // 64 x 72
  bf16* Vt = lds + 9216;   // 64 x 72, rows = dim d, cols = key
  bf16* Ps = lds + 13824;  // 4 waves x 16 x 76 (wave-private)

  const int bid = blockIdx.x;
  // r7 mapping: bh depends only on u (locality invariant); qt balanced
  // across resident sets s. (Null vs r2 mapping; kept.)
  const int u = bid & 255;
  const int s = bid >> 8;        // resident-set index 0..3
  const int v = u >> 5;          // 0..7
  const int qbase = (3 - s) << 3;
  const int qt = qbase + ((s & 1) ? v : 7 - v);
  const int bh = (u & 7) * 4 + ((u >> 3) & 3);
  const int h = bh & 15;
  const int b = bh >> 4;
  const int t0 = qt << 6;
  const int w = tid >> 6;
  const int lane = tid & 63;
  const int c = lane & 15;
  const int quad = lane >> 4;

  const int r0 = tid >> 3, c0 = (tid & 7) << 3;
  const int r1 = (tid + 256) >> 3, c1 = ((tid + 256) & 7) << 3;

  // Q fragments straight from global (once per block)
  const size_t qrow =
      ((size_t)(b * 2048 + t0 + w * 16 + c)) * 1024 + h * 64 + quad * 8;
  bf16x8 aqh[2], aql[2];
  aqh[0] = *(const bf16x8*)&qh_g[qrow];
  aqh[1] = *(const bf16x8*)&qh_g[qrow + 32];
  aql[0] = *(const bf16x8*)&ql_g[qrow];
  aql[1] = *(const bf16x8*)&ql_g[qrow + 32];

  f32x4 o[4];
  const f32x4 fzero = {0.f, 0.f, 0.f, 0.f};
#pragma unroll
  for (int j = 0; j < 4; ++j) o[j] = fzero;
  f32x4 l4 = fzero;  // row-sum accumulator (MFMA with B=ones)
  float m_i[4] = {-3e38f, -3e38f, -3e38f, -3e38f};

  bf16x8 vone;
#pragma unroll
  for (int z = 0; z < 8; ++z) vone[z] = (bf16)1.0f;

  const size_t vtb = ((size_t)(b * 16 + h)) * 64 * 2048;  // + d*2048 + t
  const size_t kband = ((size_t)(b * 2048)) * 1024 + h * 64;

  bf16x8 gk[6];  // register prefetch of next K/V tile
  {
    gk[0] = *(const bf16x8*)&kh_g[kband + (size_t)r0 * 1024 + c0];
    gk[1] = *(const bf16x8*)&kh_g[kband + (size_t)r1 * 1024 + c1];
    gk[2] = *(const bf16x8*)&kl_g[kband + (size_t)r0 * 1024 + c0];
    gk[3] = *(const bf16x8*)&kl_g[kband + (size_t)r1 * 1024 + c1];
    gk[4] = *(const bf16x8*)&vt_g[vtb + (size_t)r0 * 2048 + c0];
    gk[5] = *(const bf16x8*)&vt_g[vtb + (size_t)r1 * 2048 + c1];
  }

  for (int kt = 0; kt <= qt; ++kt) {
    __syncthreads();  // (A) prev tile's fragment reads done before restage
    *(bf16x8*)&Kh[r0 * 72 + c0] = gk[0];
    *(bf16x8*)&Kh[r1 * 72 + c1] = gk[1];
    *(bf16x8*)&Kl[r0 * 72 + c0] = gk[2];
    *(bf16x8*)&Kl[r1 * 72 + c1] = gk[3];
    *(bf16x8*)&Vt[r0 * 72 + c0] = gk[4];
    *(bf16x8*)&Vt[r1 * 72 + c1] = gk[5];
    __syncthreads();  // (B) staging visible

    if (kt < qt) {  // prefetch next tile; latency hidden behind compute
      const int kb1 = (kt + 1) << 6;
      const size_t kbase = kband + (size_t)kb1 * 1024;
      gk[0] = *(const bf16x8*)&kh_g[kbase + (size_t)r0 * 1024 + c0];
      gk[1] = *(const bf16x8*)&kh_g[kbase + (size_t)r1 * 1024 + c1];
      gk[2] = *(const bf16x8*)&kl_g[kbase + (size_t)r0 * 1024 + c0];
      gk[3] = *(const bf16x8*)&kl_g[kbase + (size_t)r1 * 1024 + c1];
      gk[4] = *(const bf16x8*)&vt_g[vtb + (size_t)r0 * 2048 + kb1 + c0];
      gk[5] = *(const bf16x8*)&vt_g[vtb + (size_t)r1 * 2048 + kb1 + c1];
    }

    bf16x8 bkh[4][2], bkl[4][2];
#pragma unroll
    for (int j = 0; j < 4; ++j)
#pragma unroll
      for (int s2 = 0; s2 < 2; ++s2) {
        bkh[j][s2] = *(const bf16x8*)&Kh[(j * 16 + c) * 72 + s2 * 32 + quad * 8];
        bkl[j][s2] = *(const bf16x8*)&Kl[(j * 16 + c) * 72 + s2 * 32 + quad * 8];
      }

    f32x4 s4[4];
#pragma unroll
    for (int j = 0; j < 4; ++j) s4[j] = fzero;
#pragma unroll
    for (int j = 0; j < 4; ++j)
#pragma unroll
      for (int s2 = 0; s2 < 2; ++s2) {
        s4[j] = __builtin_amdgcn_mfma_f32_16x16x32_bf16(aqh[s2], bkh[j][s2], s4[j], 0, 0, 0);
        s4[j] = __builtin_amdgcn_mfma_f32_16x16x32_bf16(aqh[s2], bkl[j][s2], s4[j], 0, 0, 0);
        s4[j] = __builtin_amdgcn_mfma_f32_16x16x32_bf16(aql[s2], bkh[j][s2], s4[j], 0, 0, 0);
      }

    if (kt == qt) {  // diagonal tile: strict-upper mask (t0 == kb)
#pragma unroll
      for (int j = 0; j < 4; ++j)
#pragma unroll
        for (int r = 0; r < 4; ++r)
          if (j * 16 + c > w * 16 + quad * 4 + r) s4[j][r] = -3e38f;
    }

    float p[4][4];
#pragma unroll
    for (int r = 0; r < 4; ++r) {
      float mt = fmaxf(fmaxf(s4[0][r], s4[1][r]), fmaxf(s4[2][r], s4[3][r]));
      mt = rowmax16(mt);  // DPP row reduce
      const float mn = fmaxf(m_i[r], mt);
      const float al = exp2f(m_i[r] - mn);  // logits already in log2 domain
      m_i[r] = mn;
#pragma unroll
      for (int j = 0; j < 4; ++j) p[r][j] = exp2f(s4[j][r] - mn);
      l4[r] *= al;
#pragma unroll
      for (int j = 0; j < 4; ++j) o[j][r] *= al;
    }

    // P -> wave-private region, stride 76 (conflict-free; intra-wave RAW only)
    bf16* Pw = Ps + w * 16 * 76;
#pragma unroll
    for (int r = 0; r < 4; ++r)
#pragma unroll
      for (int j = 0; j < 4; ++j)
        Pw[(quad * 4 + r) * 76 + j * 16 + c] = (bf16)p[r][j];

    bf16x8 ap[2], bv[4][2];
#pragma unroll
    for (int s2 = 0; s2 < 2; ++s2)
      ap[s2] = *(const bf16x8*)&Pw[c * 76 + s2 * 32 + quad * 8];
#pragma unroll
    for (int j = 0; j < 4; ++j)
#pragma unroll
      for (int s2 = 0; s2 < 2; ++s2)
        bv[j][s2] = *(const bf16x8*)&Vt[(j * 16 + c) * 72 + s2 * 32 + quad * 8];
    // l row-sum via MFMA (B = ones): D[m][n] = sum_k P[m][k], all n equal.
    l4 = __builtin_amdgcn_mfma_f32_16x16x32_bf16(ap[0], vone, l4, 0, 0, 0);
    l4 = __builtin_amdgcn_mfma_f32_16x16x32_bf16(ap[1], vone, l4, 0, 0, 0);
#pragma unroll
    for (int j = 0; j < 4; ++j)
#pragma unroll
      for (int s2 = 0; s2 < 2; ++s2)
        o[j] = __builtin_amdgcn_mfma_f32_16x16x32_bf16(ap[s2], bv[j][s2], o[j], 0, 0, 0);
  }

#pragma unroll
  for (int r = 0; r < 4; ++r) {
    const float inv = 1.0f / l4[r];
#pragma unroll
    for (int j = 0; j < 4; ++j) {
      const size_t oi =
          ((size_t)(b * 2048 + t0 + w * 16 + quad * 4 + r)) * 1024 + h * 64 +
          j * 16 + c;
      out[oi] = (bf16)(o[j][r] * inv);
    }
  }
}

// ---------------------------------------------------------------------------
// Workspace plan (80 MiB peak; >104 MiB previously corrupted harness memory):
//   [ 0, 8)   Wq|Wk|Wv|Wo bf16
//   [ 8,24)   h_hi|h_lo  -> (after gemm_qkv) Wf1_b|Wf2_b   (attn_cvt2 fills)
//   [24,40)   qh|ql      -> (after attn)   x1 (f32)
//   [40,72)   kh|kl|vt|attnout -> (after Wo) ff (bf16 4096x4096)
//   [72,80)   h2
// ---------------------------------------------------------------------------
extern "C" void kernel_launch(void* const* d_in, const int* in_sizes, int n_in,
                              void* d_out, int out_size, void* d_ws,
                              size_t ws_size, hipStream_t stream) {
  const float* x = (const float*)d_in[0];
  const float* g1 = (const float*)d_in[2];
  const float* b1 = (const float*)d_in[3];
  const float* g2 = (const float*)d_in[4];
  const float* b2 = (const float*)d_in[5];
  const float* Wq = (const float*)d_in[6];
  const float* Wk = (const float*)d_in[7];
  const float* Wv = (const float*)d_in[8];
  const float* Wo = (const float*)d_in[9];
  const float* Wf1 = (const float*)d_in[10];
  const float* Wf2 = (const float*)d_in[11];
  char* ws = (char*)d_ws;
  const size_t MB = 1024 * 1024;
  const size_t M1 = 1u << 20;
  bf16* Wq_b = (bf16*)ws;
  bf16* Wk_b = Wq_b + 1 * M1;
  bf16* Wv_b = Wq_b + 2 * M1;
  bf16* Wo_b = Wq_b + 3 * M1;
  bf16* h_hi = (bf16*)(ws + 8 * MB);
  bf16* h_lo = (bf16*)(ws + 16 * MB);
  bf16* Wf1_b = h_hi;  // alias: h dead after gemm_qkv; attn_cvt2 fills
  bf16* Wf2_b = h_lo;
  bf16* qh = (bf16*)(ws + 24 * MB);
  bf16* ql = (bf16*)(ws + 32 * MB);
  bf16* kh = (bf16*)(ws + 40 * MB);
  bf16* kl = (bf16*)(ws + 48 * MB);
  bf16* vt = (bf16*)(ws + 56 * MB);
  bf16* attnout = (bf16*)(ws + 64 * MB);
  float* x1 = (float*)qh;  // alias: qh/ql dead after attn
  bf16* h2 = (bf16*)(ws + 72 * MB);
  bf16* ff = kh;  // alias: kh/kl/vt/attnout dead after Wo GEMM
  float* outp = (float*)d_out;

  // 1) LN1 (split bf16 hi/lo) + cvt4 (attention weights) in one launch
  ln1_cvt4<<<8192, 256, 0, stream>>>(x, g1, b1, h_hi, h_lo, Wq, Wk, Wv, Wo,
                                     Wq_b);
  // 2) Q,K (merged split bf16, q scale = 1/8*log2e) + V^T fused — r9:
  //    2-phase dbuf BK=32 (same LDS, one barrier per k-step, overlap)
  gemm_qkv<<<dim3(24, 32), 256, 0, stream>>>(h_hi, h_lo, Wq_b, Wk_b, Wv_b, qh,
                                             ql, kh, kl, vt);
  // 3) attention (blocks 0..1023) + cvt2 FF weights (blocks 1024..9215)
  attn_cvt2<<<9216, 256, 0, stream>>>(qh, ql, kh, kl, vt, attnout, Wf1, Wf2,
                                      Wf1_b);
  // 4) x1 = x + attnout @ Wo^T   (f32; overwrites dead qh/ql) — 64N tiles
  gemm_bt64<2><<<dim3(16, 32), 256, 0, stream>>>(attnout, Wo_b, (void*)x1, x,
                                                 4096, 1024, 1024);
  // 5) LN2 -> h2 (bf16)
  ln_kernel<<<4096, 256, 0, stream>>>(x1, g2, b2, h2);
  // 6) ff = gelu(h2 @ Wff1^T)  (bf16; 128x64 tiles, 2-phase dbuf BK=64)
  gemm_bt64<3><<<dim3(64, 32), 256, 0, stream>>>(h2, Wf1_b, (void*)ff, nullptr,
                                                 4096, 4096, 1024);
  // 7) out = x1 + ff @ Wff2^T  (f32) — 64N tiles
  gemm_bt64<2><<<dim3(16, 32), 256, 0, stream>>>(ff, Wf2_b, (void*)outp, x1,
                                                 4096, 1024, 4096);
}